// Round 15
// baseline (136.678 us; speedup 1.0000x reference)
//
#include <hip/hip_runtime.h>
#include <hip/hip_bf16.h>
#include <stdint.h>
#include <math.h>

#define B_ 2
#define T_ 2048
#define C_ 1024
#define H_ 16
#define HD_ 64
#define BT_ (B_*T_)      // 4096 rows
#define N1_ (3*C_)       // 3072

typedef unsigned short u16;
typedef uint32_t u32;
typedef __attribute__((ext_vector_type(8))) short bf16x8;
typedef __attribute__((ext_vector_type(4))) float f32x4;
typedef __attribute__((ext_vector_type(16))) float f32x16;
typedef __attribute__((ext_vector_type(4))) unsigned int u32x4;

__device__ __forceinline__ u16 f2bf(float f) {
  __hip_bfloat16 h = __float2bfloat16(f);
  return *reinterpret_cast<u16*>(&h);
}
__device__ __forceinline__ float bf2f(u16 u) {
  u32 w = ((u32)u) << 16;
  return *reinterpret_cast<float*>(&w);
}
__device__ __forceinline__ u32 cvtpk(float lo, float hi) {
  u32 r;
  asm("v_cvt_pk_bf16_f32 %0, %1, %2" : "=v"(r) : "v"(lo), "v"(hi));
  return r;
}

__device__ __forceinline__ void gload_lds16(const void* g, void* l) {
  __builtin_amdgcn_global_load_lds(
      (const __attribute__((address_space(1))) uint32_t*)g,
      (__attribute__((address_space(3))) uint32_t*)l, 16, 0, 0);
}

// ---------------- cast x: fp32 -> bf16 ----------------
__global__ void cast_f32_bf16_k(const float* __restrict__ in, u16* __restrict__ out, int n) {
  int idx = (blockIdx.x * blockDim.x + threadIdx.x) * 4;
  if (idx >= n) return;
  float4 v = *reinterpret_cast<const float4*>(in + idx);
  u16 tmp[4] = {f2bf(v.x), f2bf(v.y), f2bf(v.z), f2bf(v.w)};
  *reinterpret_cast<uint2*>(out + idx) = *reinterpret_cast<const uint2*>(tmp);
}

// ---------------- transpose+cast: w (K x N fp32) -> wt (N x K bf16) ----------------
__global__ void transcast_k(const float* __restrict__ w, u16* __restrict__ wt, int K, int N) {
  __shared__ float tile[32][33];
  int n0 = blockIdx.x * 32, k0 = blockIdx.y * 32;
  int tx = threadIdx.x, ty = threadIdx.y;   // block (32,8)
#pragma unroll
  for (int i = 0; i < 4; i++)
    tile[ty + i*8][tx] = w[(size_t)(k0 + ty + i*8) * N + n0 + tx];
  __syncthreads();
#pragma unroll
  for (int i = 0; i < 4; i++)
    wt[(size_t)(n0 + ty + i*8) * K + k0 + tx] = f2bf(tile[tx][ty + i*8]);
}

// ---------------- GEMM: 2-phase double-buffered LDS, counted vmcnt (R13-proven) ----------------
template<int OUTF32>
__global__ __launch_bounds__(256) void gemm_bt(const u16* __restrict__ A, const u16* __restrict__ Bt,
                                               void* __restrict__ Cv, int M, int N, int K) {
  __shared__ u16 As[2][128*32];
  __shared__ u16 Bs[2][128*32];
  int tid = threadIdx.x, wave = tid >> 6, lane = tid & 63;
  int m0 = blockIdx.y * 128, n0 = blockIdx.x * 128;
  int wm = (wave >> 1) * 64, wn = (wave & 1) * 64;
  f32x4 acc[4][4] = {};
  int srow = lane >> 2, scol = (lane & 3) * 8;
  int fro  = (lane & 15) * 32 + (lane >> 4) * 8;

  auto stage = [&](int k0, int buf) {
#pragma unroll
    for (int i = 0; i < 2; i++) {
      gload_lds16(A  + (size_t)(m0 + i*64 + wave*16 + srow) * K + k0 + scol, &As[buf][(i*64 + wave*16) * 32]);
      gload_lds16(Bt + (size_t)(n0 + i*64 + wave*16 + srow) * K + k0 + scol, &Bs[buf][(i*64 + wave*16) * 32]);
    }
  };

  stage(0, 0);
  int nk = K >> 5;
  for (int it = 0; it < nk; ++it) {
    int cur = it & 1;
    bool nxt = (it + 1 < nk);
    if (nxt) {
      stage((it + 1) << 5, cur ^ 1);
      asm volatile("s_waitcnt vmcnt(4)" ::: "memory");
    } else {
      asm volatile("s_waitcnt vmcnt(0)" ::: "memory");
    }
    __syncthreads();
    bf16x8 af[4], bfr[4];
#pragma unroll
    for (int i = 0; i < 4; i++) af[i]  = *reinterpret_cast<const bf16x8*>(&As[cur][(wm + i*16)*32 + fro]);
#pragma unroll
    for (int j2 = 0; j2 < 4; j2++) bfr[j2] = *reinterpret_cast<const bf16x8*>(&Bs[cur][(wn + j2*16)*32 + fro]);
#pragma unroll
    for (int i = 0; i < 4; i++)
#pragma unroll
      for (int j2 = 0; j2 < 4; j2++)
        acc[i][j2] = __builtin_amdgcn_mfma_f32_16x16x32_bf16(af[i], bfr[j2], acc[i][j2], 0, 0, 0);
    __syncthreads();
  }
  int rg = (lane >> 4) * 4, cq = lane & 15;
#pragma unroll
  for (int i = 0; i < 4; i++)
#pragma unroll
    for (int j2 = 0; j2 < 4; j2++) {
      size_t basei = (size_t)(m0 + wm + i*16 + rg) * N + (size_t)(n0 + wn + j2*16 + cq);
#pragma unroll
      for (int r = 0; r < 4; r++) {
        if constexpr (OUTF32) ((float*)Cv)[basei + (size_t)r * N] = acc[i][j2][r];
        else                  ((u16*)Cv)[basei + (size_t)r * N]   = f2bf(acc[i][j2][r]);
      }
    }
}

// ---------------- causal flash attention: 3 waves, 3-way key-split, 2-DEEP prefetch ----------------
// R12/R13 geometry (proven): 1024 blocks x 192 thr, KVBLK=32, xcd=lid&7, strip pair
// {63-p,p}, 12KB/wave LDS -> 36KB/block -> 4 blocks/CU, 3 waves/SIMD.
// NEW: 2-deep pipeline. Two K LDS buffers + two V reg sets alternate by owned-tile
// parity; tile kt issues loads for kt+6 (the wave's +2nd tile, stride 3). Tile-top
// wait is vmcnt(8) (next own tile stays in flight); vmcnt(0) only on the final tile.
// Body otherwise verbatim R13 (fixed-ref softmax, permlane exchange, early-V-write).
__global__ __launch_bounds__(192, 3) void attn_kernel(const u16* __restrict__ qkv, u16* __restrict__ attnout) {
  __shared__ u16 Sm[3][6144];    // per wave: K buf0 [0..2047], K buf1 [2048..4095], V^T [4096..6143]
  int tid = threadIdx.x;
  int w = tid >> 6, lane = tid & 63;
  int q31 = lane & 31, hi = lane >> 5;
  int lid = blockIdx.x;
  int xcd = lid & 7, j = lid >> 3;
  int bh = xcd * 4 + (j & 3);
  int p = j >> 2;                // 0..31 -> strips {63-p, p}
  int b = bh >> 4, h = bh & 15;
  const u16* base = qkv + (size_t)b * T_ * N1_;

  u16* Ks = Sm[w];
  u32* Vt32 = reinterpret_cast<u32*>(Sm[w] + 4096);

  // K staging source (pre-swizzled, proven): key = 8r+(lane>>3), slot = lane&7
  const u16* ksrc = base + C_ + h*HD_ + (size_t)(lane >> 3) * N1_
                    + (size_t)(((lane & 7) ^ ((lane >> 3) & 7)) * 8);
  // V staging (R13-proven): lane covers keys {2kp2, 2kp2+1} x d = dc..dc+15
  int kp2 = lane & 15, dc = (lane >> 4) * 16;
  int vcs = kp2 >> 2, vkl = kp2 & 3;
  int vflip = (lane >> 4) & 1;
  const u16* vsrc = base + 2*C_ + h*HD_ + (size_t)(2*kp2) * N1_ + dc;
  const float QSC = 0.125f * 1.44269504088896f;
  int swr = (q31 >> 1) & 3;
  int q31f = q31 ^ ((q31 >> 4) & 1);

// one owned tile; KBO = K-buffer u16 offset (0 or 2048); VAC/VBC = this parity's V regs
#define TILE_BODY(KT, KBO, VAC, VBC)                                                    \
  do {                                                                                  \
    int kb_ = (KT) * 32;                                                                \
    bool masktile_ = ((KT) == nkt - 1);                                                 \
    if ((KT) + 3 < nkt) asm volatile("s_waitcnt vmcnt(8)" ::: "memory");                \
    else                asm volatile("s_waitcnt vmcnt(0)" ::: "memory");                \
    _Pragma("unroll")                                                                   \
    for (int r2 = 0; r2 < 2; r2++) {                                                    \
      const u16* au = (const u16*)&VAC[r2];                                             \
      const u16* bu = (const u16*)&VBC[r2];                                             \
      _Pragma("unroll")                                                                 \
      for (int i = 0; i < 8; i++) {                                                     \
        int d = dc + r2*8 + i;                                                          \
        Vt32[(d ^ vflip)*16 + ((vcs ^ ((d>>1)&3)) << 2) + vkl] =                        \
            (u32)au[i] | ((u32)bu[i] << 16);                                            \
      }                                                                                 \
    }                                                                                   \
    f32x16 st = {};                                                                     \
    __builtin_amdgcn_s_setprio(1);                                                      \
    _Pragma("unroll")                                                                   \
    for (int kk = 0; kk < 4; kk++) {                                                    \
      bf16x8 kf = *reinterpret_cast<const bf16x8*>(                                     \
          &Ks[(KBO) + q31*64 + ((((kk<<1) | hi) ^ (q31 & 7)) << 3)]);                   \
      st = __builtin_amdgcn_mfma_f32_32x32x16_bf16(kf, qf[kk], st, 0, 0, 0);            \
    }                                                                                   \
    __builtin_amdgcn_s_setprio(0);                                                      \
    asm volatile("s_waitcnt lgkmcnt(0)" ::: "memory");                                  \
    __builtin_amdgcn_sched_barrier(0);                                                  \
    if ((KT) + 6 < nkt) {                                                               \
      size_t off_ = (size_t)(kb_ + 192) * N1_;                                          \
      _Pragma("unroll")                                                                 \
      for (int r = 0; r < 4; r++)                                                       \
        gload_lds16(ksrc + off_ + (size_t)(8*r) * N1_, (char*)Ks + (KBO)*2 + r*1024);   \
      _Pragma("unroll")                                                                 \
      for (int r = 0; r < 2; r++) {                                                     \
        VAC[r] = *reinterpret_cast<const bf16x8*>(vsrc + off_ + r*8);                   \
        VBC[r] = *reinterpret_cast<const bf16x8*>(vsrc + off_ + r*8 + N1_);             \
      }                                                                                 \
    }                                                                                   \
    if (masktile_) {                                                                    \
      _Pragma("unroll")                                                                 \
      for (int r = 0; r < 16; r++) {                                                    \
        int keyg = kb_ + (r&3) + 8*(r>>2) + 4*hi;                                       \
        if (keyg > qg) st[r] = -__builtin_inff();                                       \
      }                                                                                 \
    }                                                                                   \
    float tsum_ = 0.f;                                                                  \
    _Pragma("unroll")                                                                   \
    for (int r = 0; r < 16; r++) {                                                      \
      float pp = exp2f(st[r]);                                                          \
      st[r] = pp;                                                                       \
      tsum_ += pp;                                                                      \
    }                                                                                   \
    l_run += tsum_;                                                                     \
    u32 pk[8];                                                                          \
    _Pragma("unroll")                                                                   \
    for (int m = 0; m < 8; m++) pk[m] = cvtpk(st[2*m], st[2*m+1]);                      \
    asm volatile("v_permlane32_swap_b32 %0, %1" : "+v"(pk[0]), "+v"(pk[2]));            \
    asm volatile("v_permlane32_swap_b32 %0, %1" : "+v"(pk[1]), "+v"(pk[3]));            \
    asm volatile("v_permlane32_swap_b32 %0, %1" : "+v"(pk[4]), "+v"(pk[6]));            \
    asm volatile("v_permlane32_swap_b32 %0, %1" : "+v"(pk[5]), "+v"(pk[7]));            \
    u32x4 fr0 = { pk[0], pk[1], pk[2], pk[3] };                                         \
    u32x4 fr1 = { pk[4], pk[5], pk[6], pk[7] };                                         \
    bf16x8 pf0 = __builtin_bit_cast(bf16x8, fr0);                                       \
    bf16x8 pf1 = __builtin_bit_cast(bf16x8, fr1);                                       \
    __builtin_amdgcn_s_setprio(1);                                                      \
    _Pragma("unroll")                                                                   \
    for (int dt = 0; dt < 2; dt++) {                                                    \
      _Pragma("unroll")                                                                 \
      for (int kc = 0; kc < 2; kc++) {                                                  \
        int cs = (kc << 1) | hi;                                                        \
        bf16x8 vf = *reinterpret_cast<const bf16x8*>(                                   \
            &Vt32[(32*dt + q31f)*16 + ((cs ^ swr) << 2)]);                              \
        oacc[dt] = __builtin_amdgcn_mfma_f32_32x32x16_bf16(vf, kc ? pf1 : pf0,          \
                                                           oacc[dt], 0, 0, 0);         \
      }                                                                                 \
    }                                                                                   \
    __builtin_amdgcn_s_setprio(0);                                                      \
  } while (0)

  for (int sp = 0; sp < 2; sp++) {
    int strip = sp ? p : (63 - p);
    int qbase = strip * 32;
    int qg = qbase + q31;
    int nkt = strip + 1;         // 32-key tiles this strip needs

    f32x16 oacc[2] = {};
    float l_run = 0.f;

    if (w < nkt) {
      // Q fragments pre-scaled into exp2 domain
      bf16x8 qf[4];
      {
        const u16* qrow = base + (size_t)qg * N1_ + h * HD_;
#pragma unroll
        for (int kk = 0; kk < 4; kk++) {
          bf16x8 raw = *reinterpret_cast<const bf16x8*>(qrow + kk*16 + hi*8);
          const u16* rp = (const u16*)&raw;
          u32x4 qp;
#pragma unroll
          for (int jj = 0; jj < 4; jj++)
            qp[jj] = cvtpk(bf2f(rp[2*jj]) * QSC, bf2f(rp[2*jj+1]) * QSC);
          qf[kk] = __builtin_bit_cast(bf16x8, qp);
        }
      }

      bf16x8 vA0[2], vB0[2], vA1[2], vB1[2];
      // ---- prologue: 2-deep issue (FIFO: K(w),V(w),K(w+3),V(w+3)) ----
      {
        size_t off0 = (size_t)(w * 32) * N1_;
#pragma unroll
        for (int r = 0; r < 4; r++)
          gload_lds16(ksrc + off0 + (size_t)(8*r) * N1_, (char*)Ks + r*1024);
#pragma unroll
        for (int r = 0; r < 2; r++) {
          vA0[r] = *reinterpret_cast<const bf16x8*>(vsrc + off0 + r*8);
          vB0[r] = *reinterpret_cast<const bf16x8*>(vsrc + off0 + r*8 + N1_);
        }
        if (w + 3 < nkt) {
          size_t off1 = (size_t)((w + 3) * 32) * N1_;
#pragma unroll
          for (int r = 0; r < 4; r++)
            gload_lds16(ksrc + off1 + (size_t)(8*r) * N1_, (char*)Ks + 4096 + r*1024);
#pragma unroll
          for (int r = 0; r < 2; r++) {
            vA1[r] = *reinterpret_cast<const bf16x8*>(vsrc + off1 + r*8);
            vB1[r] = *reinterpret_cast<const bf16x8*>(vsrc + off1 + r*8 + N1_);
          }
        }
      }

      int kt = w;
      while (kt < nkt) {
        TILE_BODY(kt, 0, vA0, vB0);
        kt += 3;
        if (kt >= nkt) break;
        TILE_BODY(kt, 2048, vA1, vB1);
        kt += 3;
      }
      l_run += __shfl_xor(l_run, 32);    // cross-half total (once per strip)
    }

    // ---- 3-way merge: fixed reference -> plain sums (R13-proven) ----
    __syncthreads();
    if (w) {
      float* park = (float*)Sm[w];
#pragma unroll
      for (int dt = 0; dt < 2; dt++)
#pragma unroll
        for (int r = 0; r < 16; r++) park[(dt*16 + r)*64 + lane] = oacc[dt][r];
      float* ml = (float*)Sm[0];
      ml[(w-1)*64 + lane] = l_run;
    }
    __syncthreads();
    if (w == 0) {
      const float* ml = (const float*)Sm[0];
      float linv = 1.f / (l_run + ml[lane] + ml[64 + lane]);
      const float* p1 = (const float*)Sm[1];
      const float* p2 = (const float*)Sm[2];
      u16* orow = attnout + (size_t)(b*T_ + qg) * C_ + h*HD_;
#pragma unroll
      for (int dt = 0; dt < 2; dt++)
#pragma unroll
        for (int m = 0; m < 8; m++) {
          int e0 = (dt*16 + 2*m)*64 + lane, e1 = e0 + 64;
          float v0 = (oacc[dt][2*m]   + p1[e0] + p2[e0]) * linv;
          float v1 = (oacc[dt][2*m+1] + p1[e1] + p2[e1]) * linv;
          int d = 32*dt + 2*(m&1) + 8*(m>>1) + 4*hi;
          *reinterpret_cast<u32*>(orow + d) = cvtpk(v0, v1);
        }
    }
    __syncthreads();
  }
#undef TILE_BODY
}

extern "C" void kernel_launch(void* const* d_in, const int* in_sizes, int n_in,
                              void* d_out, int out_size, void* d_ws, size_t ws_size,
                              hipStream_t stream) {
  const float* x     = (const float*)d_in[0];
  const float* w_qkv = (const float*)d_in[1];
  const float* w_out = (const float*)d_in[2];
  float* out = (float*)d_out;
  char* ws = (char*)d_ws;
  u16* xb    = (u16*)(ws);                         // 8 MB  : x bf16 (4096 x 1024)
  u16* wqkvT = (u16*)(ws + ((size_t)8  << 20));    // 6 MB  : w_qkv^T bf16 (3072 x 1024)
  u16* woutT = (u16*)(ws + ((size_t)14 << 20));    // 2 MB  : w_out^T bf16 (1024 x 1024)
  u16* qkvb  = (u16*)(ws + ((size_t)16 << 20));    // 24 MB : qkv bf16 (4096 x 3072)
  u16* attnb = (u16*)(ws + ((size_t)40 << 20));    // 8 MB  : attn out bf16 (4096 x 1024)

  cast_f32_bf16_k<<<(BT_*C_)/1024, 256, 0, stream>>>(x, xb, BT_*C_);
  transcast_k<<<dim3(N1_/32, C_/32), dim3(32, 8), 0, stream>>>(w_qkv, wqkvT, C_, N1_);
  transcast_k<<<dim3(C_/32, C_/32), dim3(32, 8), 0, stream>>>(w_out, woutT, C_, C_);
  gemm_bt<0><<<dim3(N1_/128, BT_/128), 256, 0, stream>>>(xb, wqkvT, (void*)qkvb, BT_, N1_, C_);
  attn_kernel<<<1024, 192, 0, stream>>>(qkvb, attnb);
  gemm_bt<1><<<dim3(C_/128, BT_/128), 256, 0, stream>>>(attnb, woutT, (void*)out, BT_, C_, C_);
}

// Round 16
// 130.837 us; speedup vs baseline: 1.0446x; 1.0446x over previous
//
#include <hip/hip_runtime.h>
#include <hip/hip_bf16.h>
#include <stdint.h>
#include <math.h>

#define B_ 2
#define T_ 2048
#define C_ 1024
#define H_ 16
#define HD_ 64
#define BT_ (B_*T_)      // 4096 rows
#define N1_ (3*C_)       // 3072

typedef unsigned short u16;
typedef uint32_t u32;
typedef __attribute__((ext_vector_type(8))) short bf16x8;
typedef __attribute__((ext_vector_type(4))) float f32x4;
typedef __attribute__((ext_vector_type(16))) float f32x16;
typedef __attribute__((ext_vector_type(4))) unsigned int u32x4;

__device__ __forceinline__ u16 f2bf(float f) {
  __hip_bfloat16 h = __float2bfloat16(f);
  return *reinterpret_cast<u16*>(&h);
}
__device__ __forceinline__ float bf2f(u16 u) {
  u32 w = ((u32)u) << 16;
  return *reinterpret_cast<float*>(&w);
}
__device__ __forceinline__ u32 cvtpk(float lo, float hi) {
  u32 r;
  asm("v_cvt_pk_bf16_f32 %0, %1, %2" : "=v"(r) : "v"(lo), "v"(hi));
  return r;
}

__device__ __forceinline__ void gload_lds16(const void* g, void* l) {
  __builtin_amdgcn_global_load_lds(
      (const __attribute__((address_space(1))) uint32_t*)g,
      (__attribute__((address_space(3))) uint32_t*)l, 16, 0, 0);
}

// ---------------- cast x: fp32 -> bf16 ----------------
__global__ void cast_f32_bf16_k(const float* __restrict__ in, u16* __restrict__ out, int n) {
  int idx = (blockIdx.x * blockDim.x + threadIdx.x) * 4;
  if (idx >= n) return;
  float4 v = *reinterpret_cast<const float4*>(in + idx);
  u16 tmp[4] = {f2bf(v.x), f2bf(v.y), f2bf(v.z), f2bf(v.w)};
  *reinterpret_cast<uint2*>(out + idx) = *reinterpret_cast<const uint2*>(tmp);
}

// ---------------- transpose+cast: w (K x N fp32) -> wt (N x K bf16) ----------------
__global__ void transcast_k(const float* __restrict__ w, u16* __restrict__ wt, int K, int N) {
  __shared__ float tile[32][33];
  int n0 = blockIdx.x * 32, k0 = blockIdx.y * 32;
  int tx = threadIdx.x, ty = threadIdx.y;   // block (32,8)
#pragma unroll
  for (int i = 0; i < 4; i++)
    tile[ty + i*8][tx] = w[(size_t)(k0 + ty + i*8) * N + n0 + tx];
  __syncthreads();
#pragma unroll
  for (int i = 0; i < 4; i++)
    wt[(size_t)(n0 + ty + i*8) * K + k0 + tx] = f2bf(tile[tx][ty + i*8]);
}

// ---------------- big-tile GEMM for QKV: 256x192 tile, BK=64, swizzled LDS ----------------
// A (4096 x 1024 bf16), Bt (3072 x 1024 bf16, N-major) -> C (4096 x 3072 bf16).
// Grid (16,16) = 256 blocks = exactly 1/CU; 8 waves (2M x 4N), per-wave 128x48.
// LDS 112KB: As[2][256][64], Bs[2][192][64], XOR-swizzled (slot = k8 ^ (row&7)):
// staging pre-swizzles the GLOBAL source column (gload_lds dest stays linear),
// ds_read applies the same XOR -> conflict-free b128 fragment reads.
// Counted pipeline: stage kt+1 (7 gloads) -> vmcnt(7) -> barrier -> 48 MFMA -> barrier.
__global__ __launch_bounds__(512, 2) void gemm256(const u16* __restrict__ A, const u16* __restrict__ Bt,
                                                  u16* __restrict__ Cc) {
  __shared__ u16 As[2][256*64];
  __shared__ u16 Bs[2][192*64];
  int tid = threadIdx.x, w = tid >> 6, lane = tid & 63;
  int m0 = blockIdx.y * 256, n0 = blockIdx.x * 192;
  int wm = (w >> 2) * 128, wn = (w & 3) * 48;
  f32x4 acc[8][3] = {};

  // staging: chunk c = i*512 + tid; row = c>>3, stored slot = c&7,
  // fetched global k8 = slot ^ (row&7)  (pre-swizzled source)
  size_t aoff[4];
  size_t boff[3];
#pragma unroll
  for (int i = 0; i < 4; i++) {
    int c = i*512 + tid, row = c >> 3;
    aoff[i] = (size_t)(m0 + row) * 1024 + (size_t)((((c & 7) ^ (row & 7))) * 8);
  }
#pragma unroll
  for (int i = 0; i < 3; i++) {
    int c = i*512 + tid, row = c >> 3;
    boff[i] = (size_t)(n0 + row) * 1024 + (size_t)((((c & 7) ^ (row & 7))) * 8);
  }
  int dstc = w * 64 * 16;   // wave-uniform byte base within an issue (HW adds lane*16)

  int r15 = lane & 15, kq = lane >> 4, s7 = r15 & 7;
  int slot0 = (kq ^ s7) * 8;            // elem offset within row, ksub=0 (ksub=1: ^32)
  int abase = (wm + r15) * 64;
  int bbase = (wn + r15) * 64;

  // prologue: stage K-tile 0 into buf 0
#pragma unroll
  for (int i = 0; i < 4; i++)
    gload_lds16(A + aoff[i], (char*)&As[0][0] + i*8192 + dstc);
#pragma unroll
  for (int i = 0; i < 3; i++)
    gload_lds16(Bt + boff[i], (char*)&Bs[0][0] + i*8192 + dstc);

  for (int kt = 0; kt < 16; ++kt) {
    int buf = kt & 1;
    if (kt < 15) {
      int ko = (kt + 1) * 64;
#pragma unroll
      for (int i = 0; i < 4; i++)
        gload_lds16(A + aoff[i] + ko, (char*)&As[buf ^ 1][0] + i*8192 + dstc);
#pragma unroll
      for (int i = 0; i < 3; i++)
        gload_lds16(Bt + boff[i] + ko, (char*)&Bs[buf ^ 1][0] + i*8192 + dstc);
      asm volatile("s_waitcnt vmcnt(7)" ::: "memory");   // kt landed; kt+1 in flight
    } else {
      asm volatile("s_waitcnt vmcnt(0)" ::: "memory");
    }
    __syncthreads();
#pragma unroll
    for (int ks = 0; ks < 2; ++ks) {
      int sl = slot0 ^ (ks * 32);
      bf16x8 af[8], bfv[3];
#pragma unroll
      for (int mf = 0; mf < 8; mf++)
        af[mf] = *reinterpret_cast<const bf16x8*>(&As[buf][abase + mf*1024 + sl]);
#pragma unroll
      for (int nf = 0; nf < 3; nf++)
        bfv[nf] = *reinterpret_cast<const bf16x8*>(&Bs[buf][bbase + nf*1024 + sl]);
      __builtin_amdgcn_s_setprio(1);
#pragma unroll
      for (int mf = 0; mf < 8; mf++)
#pragma unroll
        for (int nf = 0; nf < 3; nf++)
          acc[mf][nf] = __builtin_amdgcn_mfma_f32_16x16x32_bf16(af[mf], bfv[nf], acc[mf][nf], 0, 0, 0);
      __builtin_amdgcn_s_setprio(0);
    }
    __syncthreads();
  }

  int rg = kq * 4;
#pragma unroll
  for (int mf = 0; mf < 8; mf++)
#pragma unroll
    for (int nf = 0; nf < 3; nf++) {
      size_t basei = (size_t)(m0 + wm + mf*16 + rg) * N1_ + (size_t)(n0 + wn + nf*16 + r15);
#pragma unroll
      for (int r = 0; r < 4; r++)
        Cc[basei + (size_t)r * N1_] = f2bf(acc[mf][nf][r]);
    }
}

// ---------------- GEMM: 2-phase double-buffered LDS, counted vmcnt (R13-proven) ----------------
template<int OUTF32>
__global__ __launch_bounds__(256) void gemm_bt(const u16* __restrict__ A, const u16* __restrict__ Bt,
                                               void* __restrict__ Cv, int M, int N, int K) {
  __shared__ u16 As[2][128*32];
  __shared__ u16 Bs[2][128*32];
  int tid = threadIdx.x, wave = tid >> 6, lane = tid & 63;
  int m0 = blockIdx.y * 128, n0 = blockIdx.x * 128;
  int wm = (wave >> 1) * 64, wn = (wave & 1) * 64;
  f32x4 acc[4][4] = {};
  int srow = lane >> 2, scol = (lane & 3) * 8;
  int fro  = (lane & 15) * 32 + (lane >> 4) * 8;

  auto stage = [&](int k0, int buf) {
#pragma unroll
    for (int i = 0; i < 2; i++) {
      gload_lds16(A  + (size_t)(m0 + i*64 + wave*16 + srow) * K + k0 + scol, &As[buf][(i*64 + wave*16) * 32]);
      gload_lds16(Bt + (size_t)(n0 + i*64 + wave*16 + srow) * K + k0 + scol, &Bs[buf][(i*64 + wave*16) * 32]);
    }
  };

  stage(0, 0);
  int nk = K >> 5;
  for (int it = 0; it < nk; ++it) {
    int cur = it & 1;
    bool nxt = (it + 1 < nk);
    if (nxt) {
      stage((it + 1) << 5, cur ^ 1);
      asm volatile("s_waitcnt vmcnt(4)" ::: "memory");
    } else {
      asm volatile("s_waitcnt vmcnt(0)" ::: "memory");
    }
    __syncthreads();
    bf16x8 af[4], bfr[4];
#pragma unroll
    for (int i = 0; i < 4; i++) af[i]  = *reinterpret_cast<const bf16x8*>(&As[cur][(wm + i*16)*32 + fro]);
#pragma unroll
    for (int j2 = 0; j2 < 4; j2++) bfr[j2] = *reinterpret_cast<const bf16x8*>(&Bs[cur][(wn + j2*16)*32 + fro]);
#pragma unroll
    for (int i = 0; i < 4; i++)
#pragma unroll
      for (int j2 = 0; j2 < 4; j2++)
        acc[i][j2] = __builtin_amdgcn_mfma_f32_16x16x32_bf16(af[i], bfr[j2], acc[i][j2], 0, 0, 0);
    __syncthreads();
  }
  int rg = (lane >> 4) * 4, cq = lane & 15;
#pragma unroll
  for (int i = 0; i < 4; i++)
#pragma unroll
    for (int j2 = 0; j2 < 4; j2++) {
      size_t basei = (size_t)(m0 + wm + i*16 + rg) * N + (size_t)(n0 + wn + j2*16 + cq);
#pragma unroll
      for (int r = 0; r < 4; r++) {
        if constexpr (OUTF32) ((float*)Cv)[basei + (size_t)r * N] = acc[i][j2][r];
        else                  ((u16*)Cv)[basei + (size_t)r * N]   = f2bf(acc[i][j2][r]);
      }
    }
}

// ---------------- causal flash attention: R13 version (best proven, 64.5us) ----------------
__global__ __launch_bounds__(192, 3) void attn_kernel(const u16* __restrict__ qkv, u16* __restrict__ attnout) {
  __shared__ u16 Sm[3][4096];    // per wave: K tile [0..2047], V^T tile [2048..4095]
  int tid = threadIdx.x;
  int w = tid >> 6, lane = tid & 63;
  int q31 = lane & 31, hi = lane >> 5;
  int lid = blockIdx.x;
  int xcd = lid & 7, j = lid >> 3;
  int bh = xcd * 4 + (j & 3);
  int p = j >> 2;                // 0..31 -> strips {63-p, p}
  int b = bh >> 4, h = bh & 15;
  const u16* base = qkv + (size_t)b * T_ * N1_;

  u16* Ks = Sm[w];
  u32* Vt32 = reinterpret_cast<u32*>(Sm[w] + 2048);

  const u16* ksrc = base + C_ + h*HD_ + (size_t)(lane >> 3) * N1_
                    + (size_t)(((lane & 7) ^ ((lane >> 3) & 7)) * 8);
  int kp2 = lane & 15, dc = (lane >> 4) * 16;
  int vcs = kp2 >> 2, vkl = kp2 & 3;
  int vflip = (lane >> 4) & 1;
  const u16* vsrc = base + 2*C_ + h*HD_ + (size_t)(2*kp2) * N1_ + dc;
  const float QSC = 0.125f * 1.44269504088896f;
  int swr = (q31 >> 1) & 3;
  int q31f = q31 ^ ((q31 >> 4) & 1);

  for (int sp = 0; sp < 2; sp++) {
    int strip = sp ? p : (63 - p);
    int qbase = strip * 32;
    int qg = qbase + q31;
    int nkt = strip + 1;

    f32x16 oacc[2] = {};
    float l_run = 0.f;

    if (w < nkt) {
      bf16x8 qf[4];
      {
        const u16* qrow = base + (size_t)qg * N1_ + h * HD_;
#pragma unroll
        for (int kk = 0; kk < 4; kk++) {
          bf16x8 raw = *reinterpret_cast<const bf16x8*>(qrow + kk*16 + hi*8);
          const u16* rp = (const u16*)&raw;
          u32x4 qp;
#pragma unroll
          for (int jj = 0; jj < 4; jj++)
            qp[jj] = cvtpk(bf2f(rp[2*jj]) * QSC, bf2f(rp[2*jj+1]) * QSC);
          qf[kk] = __builtin_bit_cast(bf16x8, qp);
        }
      }

      bf16x8 vA[2], vB[2];
      {
        size_t off0 = (size_t)(w * 32) * N1_;
#pragma unroll
        for (int r = 0; r < 4; r++)
          gload_lds16(ksrc + off0 + (size_t)(8*r) * N1_, (char*)Ks + r*1024);
#pragma unroll
        for (int r = 0; r < 2; r++) {
          vA[r] = *reinterpret_cast<const bf16x8*>(vsrc + off0 + r*8);
          vB[r] = *reinterpret_cast<const bf16x8*>(vsrc + off0 + r*8 + N1_);
        }
      }

      for (int kt = w; kt < nkt; kt += 3) {
        int kb = kt * 32;
        bool lastown  = (kt + 3 >= nkt);
        bool masktile = (kt == nkt - 1);

        asm volatile("s_waitcnt vmcnt(0)" ::: "memory");

        // early V write (PV reads ~500cyc later)
#pragma unroll
        for (int r2 = 0; r2 < 2; r2++) {
          const u16* au = (const u16*)&vA[r2];
          const u16* bu = (const u16*)&vB[r2];
#pragma unroll
          for (int i = 0; i < 8; i++) {
            int d = dc + r2*8 + i;
            Vt32[(d ^ vflip)*16 + ((vcs ^ ((d>>1)&3)) << 2) + vkl] = (u32)au[i] | ((u32)bu[i] << 16);
          }
        }

        f32x16 st = {};
#pragma unroll
        for (int kk = 0; kk < 4; kk++) {
          bf16x8 kf = *reinterpret_cast<const bf16x8*>(
              &Ks[q31*64 + ((((kk<<1) | hi) ^ (q31 & 7)) << 3)]);
          st = __builtin_amdgcn_mfma_f32_32x32x16_bf16(kf, qf[kk], st, 0, 0, 0);
        }
        asm volatile("s_waitcnt lgkmcnt(0)" ::: "memory");
        __builtin_amdgcn_sched_barrier(0);

        if (!lastown) {
          size_t off = (size_t)(kb + 96) * N1_;
#pragma unroll
          for (int r = 0; r < 4; r++)
            gload_lds16(ksrc + off + (size_t)(8*r) * N1_, (char*)Ks + r*1024);
#pragma unroll
          for (int r = 0; r < 2; r++) {
            vA[r] = *reinterpret_cast<const bf16x8*>(vsrc + off + r*8);
            vB[r] = *reinterpret_cast<const bf16x8*>(vsrc + off + r*8 + N1_);
          }
        }

        if (masktile) {
#pragma unroll
          for (int r = 0; r < 16; r++) {
            int keyg = kb + (r&3) + 8*(r>>2) + 4*hi;
            if (keyg > qg) st[r] = -__builtin_inff();
          }
        }
        float tsum = 0.f;
#pragma unroll
        for (int r = 0; r < 16; r++) {
          float pp = exp2f(st[r]);
          st[r] = pp;
          tsum += pp;
        }
        l_run += tsum;

        u32 pk[8];
#pragma unroll
        for (int m = 0; m < 8; m++) pk[m] = cvtpk(st[2*m], st[2*m+1]);
        asm volatile("v_permlane32_swap_b32 %0, %1" : "+v"(pk[0]), "+v"(pk[2]));
        asm volatile("v_permlane32_swap_b32 %0, %1" : "+v"(pk[1]), "+v"(pk[3]));
        asm volatile("v_permlane32_swap_b32 %0, %1" : "+v"(pk[4]), "+v"(pk[6]));
        asm volatile("v_permlane32_swap_b32 %0, %1" : "+v"(pk[5]), "+v"(pk[7]));
        u32x4 fr0 = { pk[0], pk[1], pk[2], pk[3] };
        u32x4 fr1 = { pk[4], pk[5], pk[6], pk[7] };
        bf16x8 pf0 = __builtin_bit_cast(bf16x8, fr0);
        bf16x8 pf1 = __builtin_bit_cast(bf16x8, fr1);

#pragma unroll
        for (int dt = 0; dt < 2; dt++)
#pragma unroll
          for (int kc = 0; kc < 2; kc++) {
            int cs = (kc << 1) | hi;
            bf16x8 vf = *reinterpret_cast<const bf16x8*>(
                &Vt32[(32*dt + q31f)*16 + ((cs ^ swr) << 2)]);
            oacc[dt] = __builtin_amdgcn_mfma_f32_32x32x16_bf16(vf, kc ? pf1 : pf0, oacc[dt], 0, 0, 0);
          }
      }
      l_run += __shfl_xor(l_run, 32);
    }

    __syncthreads();
    if (w) {
      float* park = (float*)Sm[w];
#pragma unroll
      for (int dt = 0; dt < 2; dt++)
#pragma unroll
        for (int r = 0; r < 16; r++) park[(dt*16 + r)*64 + lane] = oacc[dt][r];
      float* ml = (float*)Sm[0];
      ml[(w-1)*64 + lane] = l_run;
    }
    __syncthreads();
    if (w == 0) {
      const float* ml = (const float*)Sm[0];
      float linv = 1.f / (l_run + ml[lane] + ml[64 + lane]);
      const float* p1 = (const float*)Sm[1];
      const float* p2 = (const float*)Sm[2];
      u16* orow = attnout + (size_t)(b*T_ + qg) * C_ + h*HD_;
#pragma unroll
      for (int dt = 0; dt < 2; dt++)
#pragma unroll
        for (int m = 0; m < 8; m++) {
          int e0 = (dt*16 + 2*m)*64 + lane, e1 = e0 + 64;
          float v0 = (oacc[dt][2*m]   + p1[e0] + p2[e0]) * linv;
          float v1 = (oacc[dt][2*m+1] + p1[e1] + p2[e1]) * linv;
          int d = 32*dt + 2*(m&1) + 8*(m>>1) + 4*hi;
          *reinterpret_cast<u32*>(orow + d) = cvtpk(v0, v1);
        }
    }
    __syncthreads();
  }
}

extern "C" void kernel_launch(void* const* d_in, const int* in_sizes, int n_in,
                              void* d_out, int out_size, void* d_ws, size_t ws_size,
                              hipStream_t stream) {
  const float* x     = (const float*)d_in[0];
  const float* w_qkv = (const float*)d_in[1];
  const float* w_out = (const float*)d_in[2];
  float* out = (float*)d_out;
  char* ws = (char*)d_ws;
  u16* xb    = (u16*)(ws);                         // 8 MB  : x bf16 (4096 x 1024)
  u16* wqkvT = (u16*)(ws + ((size_t)8  << 20));    // 6 MB  : w_qkv^T bf16 (3072 x 1024)
  u16* woutT = (u16*)(ws + ((size_t)14 << 20));    // 2 MB  : w_out^T bf16 (1024 x 1024)
  u16* qkvb  = (u16*)(ws + ((size_t)16 << 20));    // 24 MB : qkv bf16 (4096 x 3072)
  u16* attnb = (u16*)(ws + ((size_t)40 << 20));    // 8 MB  : attn out bf16 (4096 x 1024)

  cast_f32_bf16_k<<<(BT_*C_)/1024, 256, 0, stream>>>(x, xb, BT_*C_);
  transcast_k<<<dim3(N1_/32, C_/32), dim3(32, 8), 0, stream>>>(w_qkv, wqkvT, C_, N1_);
  transcast_k<<<dim3(C_/32, C_/32), dim3(32, 8), 0, stream>>>(w_out, woutT, C_, C_);
  gemm256<<<dim3(16, 16), 512, 0, stream>>>(xb, wqkvT, qkvb);
  attn_kernel<<<1024, 192, 0, stream>>>(qkvb, attnb);
  gemm_bt<1><<<dim3(C_/128, BT_/128), 256, 0, stream>>>(attnb, woutT, (void*)out, BT_, C_, C_);
}

// Round 17
// 130.706 us; speedup vs baseline: 1.0457x; 1.0010x over previous
//
#include <hip/hip_runtime.h>
#include <hip/hip_bf16.h>
#include <stdint.h>
#include <math.h>

#define B_ 2
#define T_ 2048
#define C_ 1024
#define H_ 16
#define HD_ 64
#define BT_ (B_*T_)      // 4096 rows
#define N1_ (3*C_)       // 3072

typedef unsigned short u16;
typedef uint32_t u32;
typedef __attribute__((ext_vector_type(8))) short bf16x8;
typedef __attribute__((ext_vector_type(4))) float f32x4;
typedef __attribute__((ext_vector_type(16))) float f32x16;
typedef __attribute__((ext_vector_type(4))) unsigned int u32x4;

__device__ __forceinline__ u16 f2bf(float f) {
  __hip_bfloat16 h = __float2bfloat16(f);
  return *reinterpret_cast<u16*>(&h);
}
__device__ __forceinline__ float bf2f(u16 u) {
  u32 w = ((u32)u) << 16;
  return *reinterpret_cast<float*>(&w);
}
__device__ __forceinline__ u32 cvtpk(float lo, float hi) {
  u32 r;
  asm("v_cvt_pk_bf16_f32 %0, %1, %2" : "=v"(r) : "v"(lo), "v"(hi));
  return r;
}

__device__ __forceinline__ void gload_lds16(const void* g, void* l) {
  __builtin_amdgcn_global_load_lds(
      (const __attribute__((address_space(1))) uint32_t*)g,
      (__attribute__((address_space(3))) uint32_t*)l, 16, 0, 0);
}

// raw workgroup barrier WITHOUT the __syncthreads vmcnt(0) drain (keeps counted
// prefetch in flight across barriers — the T3/T4 enabler). Compiler-level memory
// fences prevent reordering of LDS ops across it; HW waits are placed manually.
#define BARX() do { asm volatile("" ::: "memory"); __builtin_amdgcn_s_barrier(); \
                    asm volatile("" ::: "memory"); } while (0)

// ---------------- cast x: fp32 -> bf16 ----------------
__global__ void cast_f32_bf16_k(const float* __restrict__ in, u16* __restrict__ out, int n) {
  int idx = (blockIdx.x * blockDim.x + threadIdx.x) * 4;
  if (idx >= n) return;
  float4 v = *reinterpret_cast<const float4*>(in + idx);
  u16 tmp[4] = {f2bf(v.x), f2bf(v.y), f2bf(v.z), f2bf(v.w)};
  *reinterpret_cast<uint2*>(out + idx) = *reinterpret_cast<const uint2*>(tmp);
}

// ---------------- transpose+cast: w (K x N fp32) -> wt (N x K bf16) ----------------
__global__ void transcast_k(const float* __restrict__ w, u16* __restrict__ wt, int K, int N) {
  __shared__ float tile[32][33];
  int n0 = blockIdx.x * 32, k0 = blockIdx.y * 32;
  int tx = threadIdx.x, ty = threadIdx.y;   // block (32,8)
#pragma unroll
  for (int i = 0; i < 4; i++)
    tile[ty + i*8][tx] = w[(size_t)(k0 + ty + i*8) * N + n0 + tx];
  __syncthreads();
#pragma unroll
  for (int i = 0; i < 4; i++)
    wt[(size_t)(n0 + ty + i*8) * K + k0 + tx] = f2bf(tile[tx][ty + i*8]);
}

// ---------------- big-tile GEMM for QKV: 256x192, BK=64, 4-phase raw-barrier schedule ----------------
// Grid (16,16)=256 blocks=1/CU, 8 waves (2Mx4N), per-wave 128x48 (8x3 frags).
// Per K-tile, 4 phases x {stage-slice | ds_read frags | raw-bar | 12 MFMA | raw-bar}.
// Counted vmcnt(4) at phase0 (tile t's 7 stages landed, t+1's 4 A-stages in flight);
// vmcnt(0) only on the last K-tile. XOR-swizzled LDS (pre-swizzled global source).
__global__ __launch_bounds__(512, 2) void gemm256(const u16* __restrict__ A, const u16* __restrict__ Bt,
                                                  u16* __restrict__ Cc) {
  __shared__ u16 As[2][256*64];
  __shared__ u16 Bs[2][192*64];
  int tid = threadIdx.x, w = tid >> 6, lane = tid & 63;
  int m0 = blockIdx.y * 256, n0 = blockIdx.x * 192;
  int wm = (w >> 2) * 128, wn = (w & 3) * 48;
  f32x4 acc[8][3] = {};

  size_t aoff[4];
  size_t boff[3];
#pragma unroll
  for (int i = 0; i < 4; i++) {
    int c = i*512 + tid, row = c >> 3;
    aoff[i] = (size_t)(m0 + row) * 1024 + (size_t)((((c & 7) ^ (row & 7))) * 8);
  }
#pragma unroll
  for (int i = 0; i < 3; i++) {
    int c = i*512 + tid, row = c >> 3;
    boff[i] = (size_t)(n0 + row) * 1024 + (size_t)((((c & 7) ^ (row & 7))) * 8);
  }
  int dstc = w * 1024;  // wave-uniform byte base per issue (HW adds lane*16)

  int r15 = lane & 15, kq = lane >> 4;
  int slot0 = (kq ^ (r15 & 7)) * 8;
  int abase = (wm + r15) * 64;
  int bbase = (wn + r15) * 64;

  // prologue: stage K-tile 0 into buf 0 (7 gloads/thread)
#pragma unroll
  for (int i = 0; i < 4; i++)
    gload_lds16(A + aoff[i], (char*)&As[0][0] + i*8192 + dstc);
#pragma unroll
  for (int i = 0; i < 3; i++)
    gload_lds16(Bt + boff[i], (char*)&Bs[0][0] + i*8192 + dstc);

  for (int t = 0; t < 16; ++t) {
    int buf = t & 1;
    const u16* Ab = &As[buf][0];
    const u16* Bb = &Bs[buf][0];
    bf16x8 b0[3], b1[3], af[4];

    // ---- phase 0: stage A(t+1); vmcnt; bar; read ks0 mf0-3 + B(ks0); 12 MFMA ----
    if (t < 15) {
      int ko = (t + 1) * 64;
#pragma unroll
      for (int i = 0; i < 4; i++)
        gload_lds16(A + aoff[i] + ko, (char*)&As[buf ^ 1][0] + i*8192 + dstc);
      asm volatile("s_waitcnt vmcnt(4)" ::: "memory");
    } else {
      asm volatile("s_waitcnt vmcnt(0)" ::: "memory");
    }
    BARX();
#pragma unroll
    for (int nf = 0; nf < 3; nf++) b0[nf] = *reinterpret_cast<const bf16x8*>(&Bb[bbase + nf*1024 + slot0]);
#pragma unroll
    for (int mf = 0; mf < 4; mf++) af[mf] = *reinterpret_cast<const bf16x8*>(&Ab[abase + mf*1024 + slot0]);
    __builtin_amdgcn_s_setprio(1);
#pragma unroll
    for (int mf = 0; mf < 4; mf++)
#pragma unroll
      for (int nf = 0; nf < 3; nf++)
        acc[mf][nf] = __builtin_amdgcn_mfma_f32_16x16x32_bf16(af[mf], b0[nf], acc[mf][nf], 0, 0, 0);
    __builtin_amdgcn_s_setprio(0);
    BARX();

    // ---- phase 1: stage B(t+1); read ks0 mf4-7; 12 MFMA ----
    if (t < 15) {
      int ko = (t + 1) * 64;
#pragma unroll
      for (int i = 0; i < 3; i++)
        gload_lds16(Bt + boff[i] + ko, (char*)&Bs[buf ^ 1][0] + i*8192 + dstc);
    }
#pragma unroll
    for (int mf = 0; mf < 4; mf++) af[mf] = *reinterpret_cast<const bf16x8*>(&Ab[abase + (mf+4)*1024 + slot0]);
    BARX();
    __builtin_amdgcn_s_setprio(1);
#pragma unroll
    for (int mf = 0; mf < 4; mf++)
#pragma unroll
      for (int nf = 0; nf < 3; nf++)
        acc[mf+4][nf] = __builtin_amdgcn_mfma_f32_16x16x32_bf16(af[mf], b0[nf], acc[mf+4][nf], 0, 0, 0);
    __builtin_amdgcn_s_setprio(0);
    BARX();

    // ---- phase 2: read ks1 mf0-3 + B(ks1); 12 MFMA ----
    int slot1 = slot0 ^ 32;
#pragma unroll
    for (int nf = 0; nf < 3; nf++) b1[nf] = *reinterpret_cast<const bf16x8*>(&Bb[bbase + nf*1024 + slot1]);
#pragma unroll
    for (int mf = 0; mf < 4; mf++) af[mf] = *reinterpret_cast<const bf16x8*>(&Ab[abase + mf*1024 + slot1]);
    BARX();
    __builtin_amdgcn_s_setprio(1);
#pragma unroll
    for (int mf = 0; mf < 4; mf++)
#pragma unroll
      for (int nf = 0; nf < 3; nf++)
        acc[mf][nf] = __builtin_amdgcn_mfma_f32_16x16x32_bf16(af[mf], b1[nf], acc[mf][nf], 0, 0, 0);
    __builtin_amdgcn_s_setprio(0);
    BARX();

    // ---- phase 3: read ks1 mf4-7; 12 MFMA ----
#pragma unroll
    for (int mf = 0; mf < 4; mf++) af[mf] = *reinterpret_cast<const bf16x8*>(&Ab[abase + (mf+4)*1024 + slot1]);
    BARX();
    __builtin_amdgcn_s_setprio(1);
#pragma unroll
    for (int mf = 0; mf < 4; mf++)
#pragma unroll
      for (int nf = 0; nf < 3; nf++)
        acc[mf+4][nf] = __builtin_amdgcn_mfma_f32_16x16x32_bf16(af[mf], b1[nf], acc[mf+4][nf], 0, 0, 0);
    __builtin_amdgcn_s_setprio(0);
    BARX();
  }

  int rg = kq * 4;
#pragma unroll
  for (int mf = 0; mf < 8; mf++)
#pragma unroll
    for (int nf = 0; nf < 3; nf++) {
      size_t basei = (size_t)(m0 + wm + mf*16 + rg) * N1_ + (size_t)(n0 + wn + nf*16 + r15);
#pragma unroll
      for (int r = 0; r < 4; r++)
        Cc[basei + (size_t)r * N1_] = f2bf(acc[mf][nf][r]);
    }
}

// ---------------- GEMM: 2-phase dbuf, counted vmcnt + RAW barriers ----------------
template<int OUTF32>
__global__ __launch_bounds__(256) void gemm_bt(const u16* __restrict__ A, const u16* __restrict__ Bt,
                                               void* __restrict__ Cv, int M, int N, int K) {
  __shared__ u16 As[2][128*32];
  __shared__ u16 Bs[2][128*32];
  int tid = threadIdx.x, wave = tid >> 6, lane = tid & 63;
  int m0 = blockIdx.y * 128, n0 = blockIdx.x * 128;
  int wm = (wave >> 1) * 64, wn = (wave & 1) * 64;
  f32x4 acc[4][4] = {};
  int srow = lane >> 2, scol = (lane & 3) * 8;
  int fro  = (lane & 15) * 32 + (lane >> 4) * 8;

  auto stage = [&](int k0, int buf) {
#pragma unroll
    for (int i = 0; i < 2; i++) {
      gload_lds16(A  + (size_t)(m0 + i*64 + wave*16 + srow) * K + k0 + scol, &As[buf][(i*64 + wave*16) * 32]);
      gload_lds16(Bt + (size_t)(n0 + i*64 + wave*16 + srow) * K + k0 + scol, &Bs[buf][(i*64 + wave*16) * 32]);
    }
  };

  stage(0, 0);
  int nk = K >> 5;
  for (int it = 0; it < nk; ++it) {
    int cur = it & 1;
    bool nxt = (it + 1 < nk);
    if (nxt) {
      stage((it + 1) << 5, cur ^ 1);
      asm volatile("s_waitcnt vmcnt(4)" ::: "memory");
    } else {
      asm volatile("s_waitcnt vmcnt(0)" ::: "memory");
    }
    BARX();
    bf16x8 af[4], bfr[4];
#pragma unroll
    for (int i = 0; i < 4; i++) af[i]  = *reinterpret_cast<const bf16x8*>(&As[cur][(wm + i*16)*32 + fro]);
#pragma unroll
    for (int j2 = 0; j2 < 4; j2++) bfr[j2] = *reinterpret_cast<const bf16x8*>(&Bs[cur][(wn + j2*16)*32 + fro]);
    __builtin_amdgcn_s_setprio(1);
#pragma unroll
    for (int i = 0; i < 4; i++)
#pragma unroll
      for (int j2 = 0; j2 < 4; j2++)
        acc[i][j2] = __builtin_amdgcn_mfma_f32_16x16x32_bf16(af[i], bfr[j2], acc[i][j2], 0, 0, 0);
    __builtin_amdgcn_s_setprio(0);
    BARX();
  }
  int rg = (lane >> 4) * 4, cq = lane & 15;
#pragma unroll
  for (int i = 0; i < 4; i++)
#pragma unroll
    for (int j2 = 0; j2 < 4; j2++) {
      size_t basei = (size_t)(m0 + wm + i*16 + rg) * N + (size_t)(n0 + wn + j2*16 + cq);
#pragma unroll
      for (int r = 0; r < 4; r++) {
        if constexpr (OUTF32) ((float*)Cv)[basei + (size_t)r * N] = acc[i][j2][r];
        else                  ((u16*)Cv)[basei + (size_t)r * N]   = f2bf(acc[i][j2][r]);
      }
    }
}

// ---------------- causal flash attention: R13 version (best proven, 64.5us) ----------------
__global__ __launch_bounds__(192, 3) void attn_kernel(const u16* __restrict__ qkv, u16* __restrict__ attnout) {
  __shared__ u16 Sm[3][4096];    // per wave: K tile [0..2047], V^T tile [2048..4095]
  int tid = threadIdx.x;
  int w = tid >> 6, lane = tid & 63;
  int q31 = lane & 31, hi = lane >> 5;
  int lid = blockIdx.x;
  int xcd = lid & 7, j = lid >> 3;
  int bh = xcd * 4 + (j & 3);
  int p = j >> 2;                // 0..31 -> strips {63-p, p}
  int b = bh >> 4, h = bh & 15;
  const u16* base = qkv + (size_t)b * T_ * N1_;

  u16* Ks = Sm[w];
  u32* Vt32 = reinterpret_cast<u32*>(Sm[w] + 2048);

  const u16* ksrc = base + C_ + h*HD_ + (size_t)(lane >> 3) * N1_
                    + (size_t)(((lane & 7) ^ ((lane >> 3) & 7)) * 8);
  int kp2 = lane & 15, dc = (lane >> 4) * 16;
  int vcs = kp2 >> 2, vkl = kp2 & 3;
  int vflip = (lane >> 4) & 1;
  const u16* vsrc = base + 2*C_ + h*HD_ + (size_t)(2*kp2) * N1_ + dc;
  const float QSC = 0.125f * 1.44269504088896f;
  int swr = (q31 >> 1) & 3;
  int q31f = q31 ^ ((q31 >> 4) & 1);

  for (int sp = 0; sp < 2; sp++) {
    int strip = sp ? p : (63 - p);
    int qbase = strip * 32;
    int qg = qbase + q31;
    int nkt = strip + 1;

    f32x16 oacc[2] = {};
    float l_run = 0.f;

    if (w < nkt) {
      bf16x8 qf[4];
      {
        const u16* qrow = base + (size_t)qg * N1_ + h * HD_;
#pragma unroll
        for (int kk = 0; kk < 4; kk++) {
          bf16x8 raw = *reinterpret_cast<const bf16x8*>(qrow + kk*16 + hi*8);
          const u16* rp = (const u16*)&raw;
          u32x4 qp;
#pragma unroll
          for (int jj = 0; jj < 4; jj++)
            qp[jj] = cvtpk(bf2f(rp[2*jj]) * QSC, bf2f(rp[2*jj+1]) * QSC);
          qf[kk] = __builtin_bit_cast(bf16x8, qp);
        }
      }

      bf16x8 vA[2], vB[2];
      {
        size_t off0 = (size_t)(w * 32) * N1_;
#pragma unroll
        for (int r = 0; r < 4; r++)
          gload_lds16(ksrc + off0 + (size_t)(8*r) * N1_, (char*)Ks + r*1024);
#pragma unroll
        for (int r = 0; r < 2; r++) {
          vA[r] = *reinterpret_cast<const bf16x8*>(vsrc + off0 + r*8);
          vB[r] = *reinterpret_cast<const bf16x8*>(vsrc + off0 + r*8 + N1_);
        }
      }

      for (int kt = w; kt < nkt; kt += 3) {
        int kb = kt * 32;
        bool lastown  = (kt + 3 >= nkt);
        bool masktile = (kt == nkt - 1);

        asm volatile("s_waitcnt vmcnt(0)" ::: "memory");

        // early V write (PV reads ~500cyc later)
#pragma unroll
        for (int r2 = 0; r2 < 2; r2++) {
          const u16* au = (const u16*)&vA[r2];
          const u16* bu = (const u16*)&vB[r2];
#pragma unroll
          for (int i = 0; i < 8; i++) {
            int d = dc + r2*8 + i;
            Vt32[(d ^ vflip)*16 + ((vcs ^ ((d>>1)&3)) << 2) + vkl] = (u32)au[i] | ((u32)bu[i] << 16);
          }
        }

        f32x16 st = {};
#pragma unroll
        for (int kk = 0; kk < 4; kk++) {
          bf16x8 kf = *reinterpret_cast<const bf16x8*>(
              &Ks[q31*64 + ((((kk<<1) | hi) ^ (q31 & 7)) << 3)]);
          st = __builtin_amdgcn_mfma_f32_32x32x16_bf16(kf, qf[kk], st, 0, 0, 0);
        }
        asm volatile("s_waitcnt lgkmcnt(0)" ::: "memory");
        __builtin_amdgcn_sched_barrier(0);

        if (!lastown) {
          size_t off = (size_t)(kb + 96) * N1_;
#pragma unroll
          for (int r = 0; r < 4; r++)
            gload_lds16(ksrc + off + (size_t)(8*r) * N1_, (char*)Ks + r*1024);
#pragma unroll
          for (int r = 0; r < 2; r++) {
            vA[r] = *reinterpret_cast<const bf16x8*>(vsrc + off + r*8);
            vB[r] = *reinterpret_cast<const bf16x8*>(vsrc + off + r*8 + N1_);
          }
        }

        if (masktile) {
#pragma unroll
          for (int r = 0; r < 16; r++) {
            int keyg = kb + (r&3) + 8*(r>>2) + 4*hi;
            if (keyg > qg) st[r] = -__builtin_inff();
          }
        }
        float tsum = 0.f;
#pragma unroll
        for (int r = 0; r < 16; r++) {
          float pp = exp2f(st[r]);
          st[r] = pp;
          tsum += pp;
        }
        l_run += tsum;

        u32 pk[8];
#pragma unroll
        for (int m = 0; m < 8; m++) pk[m] = cvtpk(st[2*m], st[2*m+1]);
        asm volatile("v_permlane32_swap_b32 %0, %1" : "+v"(pk[0]), "+v"(pk[2]));
        asm volatile("v_permlane32_swap_b32 %0, %1" : "+v"(pk[1]), "+v"(pk[3]));
        asm volatile("v_permlane32_swap_b32 %0, %1" : "+v"(pk[4]), "+v"(pk[6]));
        asm volatile("v_permlane32_swap_b32 %0, %1" : "+v"(pk[5]), "+v"(pk[7]));
        u32x4 fr0 = { pk[0], pk[1], pk[2], pk[3] };
        u32x4 fr1 = { pk[4], pk[5], pk[6], pk[7] };
        bf16x8 pf0 = __builtin_bit_cast(bf16x8, fr0);
        bf16x8 pf1 = __builtin_bit_cast(bf16x8, fr1);

#pragma unroll
        for (int dt = 0; dt < 2; dt++)
#pragma unroll
          for (int kc = 0; kc < 2; kc++) {
            int cs = (kc << 1) | hi;
            bf16x8 vf = *reinterpret_cast<const bf16x8*>(
                &Vt32[(32*dt + q31f)*16 + ((cs ^ swr) << 2)]);
            oacc[dt] = __builtin_amdgcn_mfma_f32_32x32x16_bf16(vf, kc ? pf1 : pf0, oacc[dt], 0, 0, 0);
          }
      }
      l_run += __shfl_xor(l_run, 32);
    }

    __syncthreads();
    if (w) {
      float* park = (float*)Sm[w];
#pragma unroll
      for (int dt = 0; dt < 2; dt++)
#pragma unroll
        for (int r = 0; r < 16; r++) park[(dt*16 + r)*64 + lane] = oacc[dt][r];
      float* ml = (float*)Sm[0];
      ml[(w-1)*64 + lane] = l_run;
    }
    __syncthreads();
    if (w == 0) {
      const float* ml = (const float*)Sm[0];
      float linv = 1.f / (l_run + ml[lane] + ml[64 + lane]);
      const float* p1 = (const float*)Sm[1];
      const float* p2 = (const float*)Sm[2];
      u16* orow = attnout + (size_t)(b*T_ + qg) * C_ + h*HD_;
#pragma unroll
      for (int dt = 0; dt < 2; dt++)
#pragma unroll
        for (int m = 0; m < 8; m++) {
          int e0 = (dt*16 + 2*m)*64 + lane, e1 = e0 + 64;
          float v0 = (oacc[dt][2*m]   + p1[e0] + p2[e0]) * linv;
          float v1 = (oacc[dt][2*m+1] + p1[e1] + p2[e1]) * linv;
          int d = 32*dt + 2*(m&1) + 8*(m>>1) + 4*hi;
          *reinterpret_cast<u32*>(orow + d) = cvtpk(v0, v1);
        }
    }
    __syncthreads();
  }
}

extern "C" void kernel_launch(void* const* d_in, const int* in_sizes, int n_in,
                              void* d_out, int out_size, void* d_ws, size_t ws_size,
                              hipStream_t stream) {
  const float* x     = (const float*)d_in[0];
  const float* w_qkv = (const float*)d_in[1];
  const float* w_out = (const float*)d_in[2];
  float* out = (float*)d_out;
  char* ws = (char*)d_ws;
  u16* xb    = (u16*)(ws);                         // 8 MB  : x bf16 (4096 x 1024)
  u16* wqkvT = (u16*)(ws + ((size_t)8  << 20));    // 6 MB  : w_qkv^T bf16 (3072 x 1024)
  u16* woutT = (u16*)(ws + ((size_t)14 << 20));    // 2 MB  : w_out^T bf16 (1024 x 1024)
  u16* qkvb  = (u16*)(ws + ((size_t)16 << 20));    // 24 MB : qkv bf16 (4096 x 3072)
  u16* attnb = (u16*)(ws + ((size_t)40 << 20));    // 8 MB  : attn out bf16 (4096 x 1024)

  cast_f32_bf16_k<<<(BT_*C_)/1024, 256, 0, stream>>>(x, xb, BT_*C_);
  transcast_k<<<dim3(N1_/32, C_/32), dim3(32, 8), 0, stream>>>(w_qkv, wqkvT, C_, N1_);
  transcast_k<<<dim3(C_/32, C_/32), dim3(32, 8), 0, stream>>>(w_out, woutT, C_, C_);
  gemm256<<<dim3(16, 16), 512, 0, stream>>>(xb, wqkvT, qkvb);
  attn_kernel<<<1024, 192, 0, stream>>>(qkvb, attnb);
  gemm_bt<1><<<dim3(C_/128, BT_/128), 256, 0, stream>>>(attnb, woutT, (void*)out, BT_, C_, C_);
}

// Round 18
// 123.884 us; speedup vs baseline: 1.1033x; 1.0551x over previous
//
#include <hip/hip_runtime.h>
#include <hip/hip_bf16.h>
#include <stdint.h>
#include <math.h>

#define B_ 2
#define T_ 2048
#define C_ 1024
#define H_ 16
#define HD_ 64
#define BT_ (B_*T_)      // 4096 rows
#define N1_ (3*C_)       // 3072

typedef unsigned short u16;
typedef uint32_t u32;
typedef __attribute__((ext_vector_type(8))) short bf16x8;
typedef __attribute__((ext_vector_type(4))) float f32x4;
typedef __attribute__((ext_vector_type(16))) float f32x16;
typedef __attribute__((ext_vector_type(4))) unsigned int u32x4;

__device__ __forceinline__ u16 f2bf(float f) {
  __hip_bfloat16 h = __float2bfloat16(f);
  return *reinterpret_cast<u16*>(&h);
}
__device__ __forceinline__ float bf2f(u16 u) {
  u32 w = ((u32)u) << 16;
  return *reinterpret_cast<float*>(&w);
}
__device__ __forceinline__ u32 cvtpk(float lo, float hi) {
  u32 r;
  asm("v_cvt_pk_bf16_f32 %0, %1, %2" : "=v"(r) : "v"(lo), "v"(hi));
  return r;
}

__device__ __forceinline__ void gload_lds16(const void* g, void* l) {
  __builtin_amdgcn_global_load_lds(
      (const __attribute__((address_space(1))) uint32_t*)g,
      (__attribute__((address_space(3))) uint32_t*)l, 16, 0, 0);
}

// raw workgroup barrier WITHOUT __syncthreads' vmcnt(0) drain
#define BARX() do { asm volatile("" ::: "memory"); __builtin_amdgcn_s_barrier(); \
                    asm volatile("" ::: "memory"); } while (0)
// lgkm drain + scheduler fence (rule #18: MFMAs must not hoist past the wait)
#define LGKM0() do { asm volatile("s_waitcnt lgkmcnt(0)" ::: "memory"); \
                     __builtin_amdgcn_sched_barrier(0); } while (0)

// ---------------- cast x: fp32 -> bf16 ----------------
__global__ void cast_f32_bf16_k(const float* __restrict__ in, u16* __restrict__ out, int n) {
  int idx = (blockIdx.x * blockDim.x + threadIdx.x) * 4;
  if (idx >= n) return;
  float4 v = *reinterpret_cast<const float4*>(in + idx);
  u16 tmp[4] = {f2bf(v.x), f2bf(v.y), f2bf(v.z), f2bf(v.w)};
  *reinterpret_cast<uint2*>(out + idx) = *reinterpret_cast<const uint2*>(tmp);
}

// ---------------- transpose+cast: w (K x N fp32) -> wt (N x K bf16) ----------------
__global__ void transcast_k(const float* __restrict__ w, u16* __restrict__ wt, int K, int N) {
  __shared__ float tile[32][33];
  int n0 = blockIdx.x * 32, k0 = blockIdx.y * 32;
  int tx = threadIdx.x, ty = threadIdx.y;   // block (32,8)
#pragma unroll
  for (int i = 0; i < 4; i++)
    tile[ty + i*8][tx] = w[(size_t)(k0 + ty + i*8) * N + n0 + tx];
  __syncthreads();
#pragma unroll
  for (int i = 0; i < 4; i++)
    wt[(size_t)(n0 + ty + i*8) * K + k0 + tx] = f2bf(tile[tx][ty + i*8]);
}

// ---------------- QKV GEMM: 256x192, BK=64, m201-style phase choreography ----------------
// Per K-tile t: [vmcnt(0) cert; BARX] then 4 phases of
//   [ds-reads(this phase) | stage-slice(t+1) ; BARX ; lgkmcnt(0)+schedbar ; 12 MFMA].
// Reads hoisted BEFORE the phase barrier (latency hides under barrier-wait / other
// waves' MFMAs). Stages for t+1 issued at phases 0-1 -> a full tile of flight.
// Hazard: staging into buf^1 happens after cert-BARX, reached only after every
// wave's lgkm-drain of its buf^1 reads in tile t-1.
__global__ __launch_bounds__(512, 2) void gemm256(const u16* __restrict__ A, const u16* __restrict__ Bt,
                                                  u16* __restrict__ Cc) {
  __shared__ u16 As[2][256*64];
  __shared__ u16 Bs[2][192*64];
  int tid = threadIdx.x, w = tid >> 6, lane = tid & 63;
  int m0 = blockIdx.y * 256, n0 = blockIdx.x * 192;
  int wm = (w >> 2) * 128, wn = (w & 3) * 48;
  f32x4 acc[8][3] = {};

  size_t aoff[4];
  size_t boff[3];
#pragma unroll
  for (int i = 0; i < 4; i++) {
    int c = i*512 + tid, row = c >> 3;
    aoff[i] = (size_t)(m0 + row) * 1024 + (size_t)((((c & 7) ^ (row & 7))) * 8);
  }
#pragma unroll
  for (int i = 0; i < 3; i++) {
    int c = i*512 + tid, row = c >> 3;
    boff[i] = (size_t)(n0 + row) * 1024 + (size_t)((((c & 7) ^ (row & 7))) * 8);
  }
  int dstc = w * 1024;  // wave-uniform byte base per issue (HW adds lane*16)

  int r15 = lane & 15, kq = lane >> 4;
  int slot0 = (kq ^ (r15 & 7)) * 8;
  int abase = (wm + r15) * 64;
  int bbase = (wn + r15) * 64;

  // prologue: stage K-tile 0 into buf 0
#pragma unroll
  for (int i = 0; i < 4; i++)
    gload_lds16(A + aoff[i], (char*)&As[0][0] + i*8192 + dstc);
#pragma unroll
  for (int i = 0; i < 3; i++)
    gload_lds16(Bt + boff[i], (char*)&Bs[0][0] + i*8192 + dstc);

  for (int t = 0; t < 16; ++t) {
    int buf = t & 1;
    const u16* Ab = &As[buf][0];
    const u16* Bb = &Bs[buf][0];
    int slot1 = slot0 ^ 32;
    bf16x8 b0[3], b1[3], a0[4], a1[4], a2[4], a3[4];

    // ---- cert: my stages for tile t landed; all waves' buf^1 reads drained ----
    asm volatile("s_waitcnt vmcnt(0)" ::: "memory");
    BARX();

    // ---- phase 0: reads(ks0, mf0-3, B.ks0) | stage A(t+1); bar; 12 MFMA ----
#pragma unroll
    for (int nf = 0; nf < 3; nf++) b0[nf] = *reinterpret_cast<const bf16x8*>(&Bb[bbase + nf*1024 + slot0]);
#pragma unroll
    for (int mf = 0; mf < 4; mf++) a0[mf] = *reinterpret_cast<const bf16x8*>(&Ab[abase + mf*1024 + slot0]);
    if (t < 15) {
      int ko = (t + 1) * 64;
#pragma unroll
      for (int i = 0; i < 4; i++)
        gload_lds16(A + aoff[i] + ko, (char*)&As[buf ^ 1][0] + i*8192 + dstc);
    }
    BARX();
    LGKM0();
    __builtin_amdgcn_s_setprio(1);
#pragma unroll
    for (int mf = 0; mf < 4; mf++)
#pragma unroll
      for (int nf = 0; nf < 3; nf++)
        acc[mf][nf] = __builtin_amdgcn_mfma_f32_16x16x32_bf16(a0[mf], b0[nf], acc[mf][nf], 0, 0, 0);
    __builtin_amdgcn_s_setprio(0);

    // ---- phase 1: reads(ks0, mf4-7) | stage B(t+1); bar; 12 MFMA ----
#pragma unroll
    for (int mf = 0; mf < 4; mf++) a1[mf] = *reinterpret_cast<const bf16x8*>(&Ab[abase + (mf+4)*1024 + slot0]);
    if (t < 15) {
      int ko = (t + 1) * 64;
#pragma unroll
      for (int i = 0; i < 3; i++)
        gload_lds16(Bt + boff[i] + ko, (char*)&Bs[buf ^ 1][0] + i*8192 + dstc);
    }
    BARX();
    LGKM0();
    __builtin_amdgcn_s_setprio(1);
#pragma unroll
    for (int mf = 0; mf < 4; mf++)
#pragma unroll
      for (int nf = 0; nf < 3; nf++)
        acc[mf+4][nf] = __builtin_amdgcn_mfma_f32_16x16x32_bf16(a1[mf], b0[nf], acc[mf+4][nf], 0, 0, 0);
    __builtin_amdgcn_s_setprio(0);

    // ---- phase 2: reads(ks1, mf0-3, B.ks1); bar; 12 MFMA ----
#pragma unroll
    for (int nf = 0; nf < 3; nf++) b1[nf] = *reinterpret_cast<const bf16x8*>(&Bb[bbase + nf*1024 + slot1]);
#pragma unroll
    for (int mf = 0; mf < 4; mf++) a2[mf] = *reinterpret_cast<const bf16x8*>(&Ab[abase + mf*1024 + slot1]);
    BARX();
    LGKM0();
    __builtin_amdgcn_s_setprio(1);
#pragma unroll
    for (int mf = 0; mf < 4; mf++)
#pragma unroll
      for (int nf = 0; nf < 3; nf++)
        acc[mf][nf] = __builtin_amdgcn_mfma_f32_16x16x32_bf16(a2[mf], b1[nf], acc[mf][nf], 0, 0, 0);
    __builtin_amdgcn_s_setprio(0);

    // ---- phase 3: reads(ks1, mf4-7); bar; 12 MFMA ----
#pragma unroll
    for (int mf = 0; mf < 4; mf++) a3[mf] = *reinterpret_cast<const bf16x8*>(&Ab[abase + (mf+4)*1024 + slot1]);
    BARX();
    LGKM0();
    __builtin_amdgcn_s_setprio(1);
#pragma unroll
    for (int mf = 0; mf < 4; mf++)
#pragma unroll
      for (int nf = 0; nf < 3; nf++)
        acc[mf+4][nf] = __builtin_amdgcn_mfma_f32_16x16x32_bf16(a3[mf], b1[nf], acc[mf+4][nf], 0, 0, 0);
    __builtin_amdgcn_s_setprio(0);
  }

  int rg = kq * 4;
#pragma unroll
  for (int mf = 0; mf < 8; mf++)
#pragma unroll
    for (int nf = 0; nf < 3; nf++) {
      size_t basei = (size_t)(m0 + wm + mf*16 + rg) * N1_ + (size_t)(n0 + wn + nf*16 + r15);
#pragma unroll
      for (int r = 0; r < 4; r++)
        Cc[basei + (size_t)r * N1_] = f2bf(acc[mf][nf][r]);
    }
}

// ---------------- out-proj GEMM: cert + reads-hoisted single-phase tiles ----------------
template<int OUTF32>
__global__ __launch_bounds__(256) void gemm_bt(const u16* __restrict__ A, const u16* __restrict__ Bt,
                                               void* __restrict__ Cv, int M, int N, int K) {
  __shared__ u16 As[2][128*32];
  __shared__ u16 Bs[2][128*32];
  int tid = threadIdx.x, wave = tid >> 6, lane = tid & 63;
  int m0 = blockIdx.y * 128, n0 = blockIdx.x * 128;
  int wm = (wave >> 1) * 64, wn = (wave & 1) * 64;
  f32x4 acc[4][4] = {};
  int srow = lane >> 2, scol = (lane & 3) * 8;
  int fro  = (lane & 15) * 32 + (lane >> 4) * 8;

  auto stage = [&](int k0, int buf) {
#pragma unroll
    for (int i = 0; i < 2; i++) {
      gload_lds16(A  + (size_t)(m0 + i*64 + wave*16 + srow) * K + k0 + scol, &As[buf][(i*64 + wave*16) * 32]);
      gload_lds16(Bt + (size_t)(n0 + i*64 + wave*16 + srow) * K + k0 + scol, &Bs[buf][(i*64 + wave*16) * 32]);
    }
  };

  stage(0, 0);
  int nk = K >> 5;
  for (int it = 0; it < nk; ++it) {
    int cur = it & 1;
    // cert my stages for tile it; all waves' reads of cur^1 drained
    asm volatile("s_waitcnt vmcnt(0)" ::: "memory");
    BARX();
    bf16x8 af[4], bfr[4];
#pragma unroll
    for (int i = 0; i < 4; i++) af[i]  = *reinterpret_cast<const bf16x8*>(&As[cur][(wm + i*16)*32 + fro]);
#pragma unroll
    for (int j2 = 0; j2 < 4; j2++) bfr[j2] = *reinterpret_cast<const bf16x8*>(&Bs[cur][(wn + j2*16)*32 + fro]);
    if (it + 1 < nk) stage((it + 1) << 5, cur ^ 1);
    BARX();
    LGKM0();
    __builtin_amdgcn_s_setprio(1);
#pragma unroll
    for (int i = 0; i < 4; i++)
#pragma unroll
      for (int j2 = 0; j2 < 4; j2++)
        acc[i][j2] = __builtin_amdgcn_mfma_f32_16x16x32_bf16(af[i], bfr[j2], acc[i][j2], 0, 0, 0);
    __builtin_amdgcn_s_setprio(0);
  }
  int rg = (lane >> 4) * 4, cq = lane & 15;
#pragma unroll
  for (int i = 0; i < 4; i++)
#pragma unroll
    for (int j2 = 0; j2 < 4; j2++) {
      size_t basei = (size_t)(m0 + wm + i*16 + rg) * N + (size_t)(n0 + wn + j2*16 + cq);
#pragma unroll
      for (int r = 0; r < 4; r++) {
        if constexpr (OUTF32) ((float*)Cv)[basei + (size_t)r * N] = acc[i][j2][r];
        else                  ((u16*)Cv)[basei + (size_t)r * N]   = f2bf(acc[i][j2][r]);
      }
    }
}

// ---------------- causal flash attention: R13 version (best proven, 64.5us) ----------------
__global__ __launch_bounds__(192, 3) void attn_kernel(const u16* __restrict__ qkv, u16* __restrict__ attnout) {
  __shared__ u16 Sm[3][4096];    // per wave: K tile [0..2047], V^T tile [2048..4095]
  int tid = threadIdx.x;
  int w = tid >> 6, lane = tid & 63;
  int q31 = lane & 31, hi = lane >> 5;
  int lid = blockIdx.x;
  int xcd = lid & 7, j = lid >> 3;
  int bh = xcd * 4 + (j & 3);
  int p = j >> 2;                // 0..31 -> strips {63-p, p}
  int b = bh >> 4, h = bh & 15;
  const u16* base = qkv + (size_t)b * T_ * N1_;

  u16* Ks = Sm[w];
  u32* Vt32 = reinterpret_cast<u32*>(Sm[w] + 2048);

  const u16* ksrc = base + C_ + h*HD_ + (size_t)(lane >> 3) * N1_
                    + (size_t)(((lane & 7) ^ ((lane >> 3) & 7)) * 8);
  int kp2 = lane & 15, dc = (lane >> 4) * 16;
  int vcs = kp2 >> 2, vkl = kp2 & 3;
  int vflip = (lane >> 4) & 1;
  const u16* vsrc = base + 2*C_ + h*HD_ + (size_t)(2*kp2) * N1_ + dc;
  const float QSC = 0.125f * 1.44269504088896f;
  int swr = (q31 >> 1) & 3;
  int q31f = q31 ^ ((q31 >> 4) & 1);

  for (int sp = 0; sp < 2; sp++) {
    int strip = sp ? p : (63 - p);
    int qbase = strip * 32;
    int qg = qbase + q31;
    int nkt = strip + 1;

    f32x16 oacc[2] = {};
    float l_run = 0.f;

    if (w < nkt) {
      bf16x8 qf[4];
      {
        const u16* qrow = base + (size_t)qg * N1_ + h * HD_;
#pragma unroll
        for (int kk = 0; kk < 4; kk++) {
          bf16x8 raw = *reinterpret_cast<const bf16x8*>(qrow + kk*16 + hi*8);
          const u16* rp = (const u16*)&raw;
          u32x4 qp;
#pragma unroll
          for (int jj = 0; jj < 4; jj++)
            qp[jj] = cvtpk(bf2f(rp[2*jj]) * QSC, bf2f(rp[2*jj+1]) * QSC);
          qf[kk] = __builtin_bit_cast(bf16x8, qp);
        }
      }

      bf16x8 vA[2], vB[2];
      {
        size_t off0 = (size_t)(w * 32) * N1_;
#pragma unroll
        for (int r = 0; r < 4; r++)
          gload_lds16(ksrc + off0 + (size_t)(8*r) * N1_, (char*)Ks + r*1024);
#pragma unroll
        for (int r = 0; r < 2; r++) {
          vA[r] = *reinterpret_cast<const bf16x8*>(vsrc + off0 + r*8);
          vB[r] = *reinterpret_cast<const bf16x8*>(vsrc + off0 + r*8 + N1_);
        }
      }

      for (int kt = w; kt < nkt; kt += 3) {
        int kb = kt * 32;
        bool lastown  = (kt + 3 >= nkt);
        bool masktile = (kt == nkt - 1);

        asm volatile("s_waitcnt vmcnt(0)" ::: "memory");

        // early V write (PV reads ~500cyc later)
#pragma unroll
        for (int r2 = 0; r2 < 2; r2++) {
          const u16* au = (const u16*)&vA[r2];
          const u16* bu = (const u16*)&vB[r2];
#pragma unroll
          for (int i = 0; i < 8; i++) {
            int d = dc + r2*8 + i;
            Vt32[(d ^ vflip)*16 + ((vcs ^ ((d>>1)&3)) << 2) + vkl] = (u32)au[i] | ((u32)bu[i] << 16);
          }
        }

        f32x16 st = {};
#pragma unroll
        for (int kk = 0; kk < 4; kk++) {
          bf16x8 kf = *reinterpret_cast<const bf16x8*>(
              &Ks[q31*64 + ((((kk<<1) | hi) ^ (q31 & 7)) << 3)]);
          st = __builtin_amdgcn_mfma_f32_32x32x16_bf16(kf, qf[kk], st, 0, 0, 0);
        }
        asm volatile("s_waitcnt lgkmcnt(0)" ::: "memory");
        __builtin_amdgcn_sched_barrier(0);

        if (!lastown) {
          size_t off = (size_t)(kb + 96) * N1_;
#pragma unroll
          for (int r = 0; r < 4; r++)
            gload_lds16(ksrc + off + (size_t)(8*r) * N1_, (char*)Ks + r*1024);
#pragma unroll
          for (int r = 0; r < 2; r++) {
            vA[r] = *reinterpret_cast<const bf16x8*>(vsrc + off + r*8);
            vB[r] = *reinterpret_cast<const bf16x8*>(vsrc + off + r*8 + N1_);
          }
        }

        if (masktile) {
#pragma unroll
          for (int r = 0; r < 16; r++) {
            int keyg = kb + (r&3) + 8*(r>>2) + 4*hi;
            if (keyg > qg) st[r] = -__builtin_inff();
          }
        }
        float tsum = 0.f;
#pragma unroll
        for (int r = 0; r < 16; r++) {
          float pp = exp2f(st[r]);
          st[r] = pp;
          tsum += pp;
        }
        l_run += tsum;

        u32 pk[8];
#pragma unroll
        for (int m = 0; m < 8; m++) pk[m] = cvtpk(st[2*m], st[2*m+1]);
        asm volatile("v_permlane32_swap_b32 %0, %1" : "+v"(pk[0]), "+v"(pk[2]));
        asm volatile("v_permlane32_swap_b32 %0, %1" : "+v"(pk[1]), "+v"(pk[3]));
        asm volatile("v_permlane32_swap_b32 %0, %1" : "+v"(pk[4]), "+v"(pk[6]));
        asm volatile("v_permlane32_swap_b32 %0, %1" : "+v"(pk[5]), "+v"(pk[7]));
        u32x4 fr0 = { pk[0], pk[1], pk[2], pk[3] };
        u32x4 fr1 = { pk[4], pk[5], pk[6], pk[7] };
        bf16x8 pf0 = __builtin_bit_cast(bf16x8, fr0);
        bf16x8 pf1 = __builtin_bit_cast(bf16x8, fr1);

#pragma unroll
        for (int dt = 0; dt < 2; dt++)
#pragma unroll
          for (int kc = 0; kc < 2; kc++) {
            int cs = (kc << 1) | hi;
            bf16x8 vf = *reinterpret_cast<const bf16x8*>(
                &Vt32[(32*dt + q31f)*16 + ((cs ^ swr) << 2)]);
            oacc[dt] = __builtin_amdgcn_mfma_f32_32x32x16_bf16(vf, kc ? pf1 : pf0, oacc[dt], 0, 0, 0);
          }
      }
      l_run += __shfl_xor(l_run, 32);
    }

    __syncthreads();
    if (w) {
      float* park = (float*)Sm[w];
#pragma unroll
      for (int dt = 0; dt < 2; dt++)
#pragma unroll
        for (int r = 0; r < 16; r++) park[(dt*16 + r)*64 + lane] = oacc[dt][r];
      float* ml = (float*)Sm[0];
      ml[(w-1)*64 + lane] = l_run;
    }
    __syncthreads();
    if (w == 0) {
      const float* ml = (const float*)Sm[0];
      float linv = 1.f / (l_run + ml[lane] + ml[64 + lane]);
      const float* p1 = (const float*)Sm[1];
      const float* p2 = (const float*)Sm[2];
      u16* orow = attnout + (size_t)(b*T_ + qg) * C_ + h*HD_;
#pragma unroll
      for (int dt = 0; dt < 2; dt++)
#pragma unroll
        for (int m = 0; m < 8; m++) {
          int e0 = (dt*16 + 2*m)*64 + lane, e1 = e0 + 64;
          float v0 = (oacc[dt][2*m]   + p1[e0] + p2[e0]) * linv;
          float v1 = (oacc[dt][2*m+1] + p1[e1] + p2[e1]) * linv;
          int d = 32*dt + 2*(m&1) + 8*(m>>1) + 4*hi;
          *reinterpret_cast<u32*>(orow + d) = cvtpk(v0, v1);
        }
    }
    __syncthreads();
  }
}

extern "C" void kernel_launch(void* const* d_in, const int* in_sizes, int n_in,
                              void* d_out, int out_size, void* d_ws, size_t ws_size,
                              hipStream_t stream) {
  const float* x     = (const float*)d_in[0];
  const float* w_qkv = (const float*)d_in[1];
  const float* w_out = (const float*)d_in[2];
  float* out = (float*)d_out;
  char* ws = (char*)d_ws;
  u16* xb    = (u16*)(ws);                         // 8 MB  : x bf16 (4096 x 1024)
  u16* wqkvT = (u16*)(ws + ((size_t)8  << 20));    // 6 MB  : w_qkv^T bf16 (3072 x 1024)
  u16* woutT = (u16*)(ws + ((size_t)14 << 20));    // 2 MB  : w_out^T bf16 (1024 x 1024)
  u16* qkvb  = (u16*)(ws + ((size_t)16 << 20));    // 24 MB : qkv bf16 (4096 x 3072)
  u16* attnb = (u16*)(ws + ((size_t)40 << 20));    // 8 MB  : attn out bf16 (4096 x 1024)

  cast_f32_bf16_k<<<(BT_*C_)/1024, 256, 0, stream>>>(x, xb, BT_*C_);
  transcast_k<<<dim3(N1_/32, C_/32), dim3(32, 8), 0, stream>>>(w_qkv, wqkvT, C_, N1_);
  transcast_k<<<dim3(C_/32, C_/32), dim3(32, 8), 0, stream>>>(w_out, woutT, C_, C_);
  gemm256<<<dim3(16, 16), 512, 0, stream>>>(xb, wqkvT, qkvb);
  attn_kernel<<<1024, 192, 0, stream>>>(qkvb, attnb);
  gemm_bt<1><<<dim3(C_/128, BT_/128), 256, 0, stream>>>(attnb, woutT, (void*)out, BT_, C_, C_);
}

// Round 19
// 113.606 us; speedup vs baseline: 1.2031x; 1.0905x over previous
//
#include <hip/hip_runtime.h>
#include <hip/hip_bf16.h>
#include <stdint.h>
#include <math.h>

#define B_ 2
#define T_ 2048
#define C_ 1024
#define H_ 16
#define HD_ 64
#define BT_ (B_*T_)      // 4096 rows
#define N1_ (3*C_)       // 3072

typedef unsigned short u16;
typedef uint32_t u32;
typedef __attribute__((ext_vector_type(8))) short bf16x8;
typedef __attribute__((ext_vector_type(4))) float f32x4;
typedef __attribute__((ext_vector_type(16))) float f32x16;
typedef __attribute__((ext_vector_type(4))) unsigned int u32x4;

__device__ __forceinline__ u16 f2bf(float f) {
  __hip_bfloat16 h = __float2bfloat16(f);
  return *reinterpret_cast<u16*>(&h);
}
__device__ __forceinline__ float bf2f(u16 u) {
  u32 w = ((u32)u) << 16;
  return *reinterpret_cast<float*>(&w);
}
__device__ __forceinline__ u32 cvtpk(float lo, float hi) {
  u32 r;
  asm("v_cvt_pk_bf16_f32 %0, %1, %2" : "=v"(r) : "v"(lo), "v"(hi));
  return r;
}
__device__ __forceinline__ float exp2v(float x) {   // exact v_exp_f32 (2^x); -inf -> 0
  float r;
  asm("v_exp_f32 %0, %1" : "=v"(r) : "v"(x));
  return r;
}

__device__ __forceinline__ void gload_lds16(const void* g, void* l) {
  __builtin_amdgcn_global_load_lds(
      (const __attribute__((address_space(1))) uint32_t*)g,
      (__attribute__((address_space(3))) uint32_t*)l, 16, 0, 0);
}

// raw workgroup barrier WITHOUT __syncthreads' vmcnt(0) drain
#define BARX() do { asm volatile("" ::: "memory"); __builtin_amdgcn_s_barrier(); \
                    asm volatile("" ::: "memory"); } while (0)
// lgkm drain + scheduler fence (rule #18)
#define LGKM0() do { asm volatile("s_waitcnt lgkmcnt(0)" ::: "memory"); \
                     __builtin_amdgcn_sched_barrier(0); } while (0)

// ---------------- fused prep: cast x + transpose-cast both weights ----------------
// flat grid of 256-thr blocks: [0,4096) cast x; [4096,7168) w_qkv tiles; [7168,8192) w_out.
__global__ __launch_bounds__(256) void prep_k(const float* __restrict__ x,
                                              const float* __restrict__ w_qkv,
                                              const float* __restrict__ w_out,
                                              u16* __restrict__ xb,
                                              u16* __restrict__ wqkvT,
                                              u16* __restrict__ woutT) {
  __shared__ float tile[32][33];
  int bid = blockIdx.x;
  if (bid < 4096) {
    int idx = bid * 1024 + threadIdx.x * 4;
    float4 v = *reinterpret_cast<const float4*>(x + idx);
    u16 tmp[4] = {f2bf(v.x), f2bf(v.y), f2bf(v.z), f2bf(v.w)};
    *reinterpret_cast<uint2*>(xb + idx) = *reinterpret_cast<const uint2*>(tmp);
    return;
  }
  const float* w;
  u16* wt;
  int N, tb;
  if (bid < 7168) { tb = bid - 4096; w = w_qkv; wt = wqkvT; N = N1_; }
  else            { tb = bid - 7168; w = w_out; wt = woutT; N = C_;  }
  int nx = N >> 5;
  int n0 = (tb % nx) * 32, k0 = (tb / nx) * 32;
  int tx = threadIdx.x & 31, ty = threadIdx.x >> 5;
#pragma unroll
  for (int i = 0; i < 4; i++)
    tile[ty + i*8][tx] = w[(size_t)(k0 + ty + i*8) * N + n0 + tx];
  __syncthreads();
#pragma unroll
  for (int i = 0; i < 4; i++)
    wt[(size_t)(n0 + ty + i*8) * 1024 + k0 + tx] = f2bf(tile[tx][ty + i*8]);
}

// ---------------- QKV GEMM: 256x192, BK=64, 2-phase choreography ----------------
// Per K-tile t: [vmcnt(0) cert; BARX] then 2 phases of
//   [ds-reads(ks) | stage(t+1, phase0 only) ; BARX ; lgkmcnt(0)+schedbar ; 24 MFMA].
__global__ __launch_bounds__(512, 2) void gemm256(const u16* __restrict__ A, const u16* __restrict__ Bt,
                                                  u16* __restrict__ Cc) {
  __shared__ u16 As[2][256*64];
  __shared__ u16 Bs[2][192*64];
  int tid = threadIdx.x, w = tid >> 6, lane = tid & 63;
  int m0 = blockIdx.y * 256, n0 = blockIdx.x * 192;
  int wm = (w >> 2) * 128, wn = (w & 3) * 48;
  f32x4 acc[8][3] = {};

  size_t aoff[4];
  size_t boff[3];
#pragma unroll
  for (int i = 0; i < 4; i++) {
    int c = i*512 + tid, row = c >> 3;
    aoff[i] = (size_t)(m0 + row) * 1024 + (size_t)((((c & 7) ^ (row & 7))) * 8);
  }
#pragma unroll
  for (int i = 0; i < 3; i++) {
    int c = i*512 + tid, row = c >> 3;
    boff[i] = (size_t)(n0 + row) * 1024 + (size_t)((((c & 7) ^ (row & 7))) * 8);
  }
  int dstc = w * 1024;

  int r15 = lane & 15, kq = lane >> 4;
  int slot0 = (kq ^ (r15 & 7)) * 8;
  int abase = (wm + r15) * 64;
  int bbase = (wn + r15) * 64;

  // prologue: stage K-tile 0 into buf 0
#pragma unroll
  for (int i = 0; i < 4; i++)
    gload_lds16(A + aoff[i], (char*)&As[0][0] + i*8192 + dstc);
#pragma unroll
  for (int i = 0; i < 3; i++)
    gload_lds16(Bt + boff[i], (char*)&Bs[0][0] + i*8192 + dstc);

  for (int t = 0; t < 16; ++t) {
    int buf = t & 1;
    const u16* Ab = &As[buf][0];
    const u16* Bb = &Bs[buf][0];
    int slot1 = slot0 ^ 32;
    bf16x8 af[8], bfv[3];

    // ---- cert: stages for tile t landed; all waves' buf^1 reads drained ----
    asm volatile("s_waitcnt vmcnt(0)" ::: "memory");
    BARX();

    // ---- phase 0: reads(ks0) | stage all of t+1; bar; 24 MFMA ----
#pragma unroll
    for (int nf = 0; nf < 3; nf++) bfv[nf] = *reinterpret_cast<const bf16x8*>(&Bb[bbase + nf*1024 + slot0]);
#pragma unroll
    for (int mf = 0; mf < 8; mf++) af[mf] = *reinterpret_cast<const bf16x8*>(&Ab[abase + mf*1024 + slot0]);
    if (t < 15) {
      int ko = (t + 1) * 64;
#pragma unroll
      for (int i = 0; i < 4; i++)
        gload_lds16(A + aoff[i] + ko, (char*)&As[buf ^ 1][0] + i*8192 + dstc);
#pragma unroll
      for (int i = 0; i < 3; i++)
        gload_lds16(Bt + boff[i] + ko, (char*)&Bs[buf ^ 1][0] + i*8192 + dstc);
    }
    BARX();
    LGKM0();
    __builtin_amdgcn_s_setprio(1);
#pragma unroll
    for (int mf = 0; mf < 8; mf++)
#pragma unroll
      for (int nf = 0; nf < 3; nf++)
        acc[mf][nf] = __builtin_amdgcn_mfma_f32_16x16x32_bf16(af[mf], bfv[nf], acc[mf][nf], 0, 0, 0);
    __builtin_amdgcn_s_setprio(0);

    // ---- phase 1: reads(ks1); bar; 24 MFMA ----
#pragma unroll
    for (int nf = 0; nf < 3; nf++) bfv[nf] = *reinterpret_cast<const bf16x8*>(&Bb[bbase + nf*1024 + slot1]);
#pragma unroll
    for (int mf = 0; mf < 8; mf++) af[mf] = *reinterpret_cast<const bf16x8*>(&Ab[abase + mf*1024 + slot1]);
    BARX();
    LGKM0();
    __builtin_amdgcn_s_setprio(1);
#pragma unroll
    for (int mf = 0; mf < 8; mf++)
#pragma unroll
      for (int nf = 0; nf < 3; nf++)
        acc[mf][nf] = __builtin_amdgcn_mfma_f32_16x16x32_bf16(af[mf], bfv[nf], acc[mf][nf], 0, 0, 0);
    __builtin_amdgcn_s_setprio(0);
  }

  int rg = kq * 4;
#pragma unroll
  for (int mf = 0; mf < 8; mf++)
#pragma unroll
    for (int nf = 0; nf < 3; nf++) {
      size_t basei = (size_t)(m0 + wm + mf*16 + rg) * N1_ + (size_t)(n0 + wn + nf*16 + r15);
#pragma unroll
      for (int r = 0; r < 4; r++)
        Cc[basei + (size_t)r * N1_] = f2bf(acc[mf][nf][r]);
    }
}

// ---------------- out-proj GEMM: cert + reads-hoisted single-phase tiles (R18-proven) ----------------
template<int OUTF32>
__global__ __launch_bounds__(256) void gemm_bt(const u16* __restrict__ A, const u16* __restrict__ Bt,
                                               void* __restrict__ Cv, int M, int N, int K) {
  __shared__ u16 As[2][128*32];
  __shared__ u16 Bs[2][128*32];
  int tid = threadIdx.x, wave = tid >> 6, lane = tid & 63;
  int m0 = blockIdx.y * 128, n0 = blockIdx.x * 128;
  int wm = (wave >> 1) * 64, wn = (wave & 1) * 64;
  f32x4 acc[4][4] = {};
  int srow = lane >> 2, scol = (lane & 3) * 8;
  int fro  = (lane & 15) * 32 + (lane >> 4) * 8;

  auto stage = [&](int k0, int buf) {
#pragma unroll
    for (int i = 0; i < 2; i++) {
      gload_lds16(A  + (size_t)(m0 + i*64 + wave*16 + srow) * K + k0 + scol, &As[buf][(i*64 + wave*16) * 32]);
      gload_lds16(Bt + (size_t)(n0 + i*64 + wave*16 + srow) * K + k0 + scol, &Bs[buf][(i*64 + wave*16) * 32]);
    }
  };

  stage(0, 0);
  int nk = K >> 5;
  for (int it = 0; it < nk; ++it) {
    int cur = it & 1;
    asm volatile("s_waitcnt vmcnt(0)" ::: "memory");
    BARX();
    bf16x8 af[4], bfr[4];
#pragma unroll
    for (int i = 0; i < 4; i++) af[i]  = *reinterpret_cast<const bf16x8*>(&As[cur][(wm + i*16)*32 + fro]);
#pragma unroll
    for (int j2 = 0; j2 < 4; j2++) bfr[j2] = *reinterpret_cast<const bf16x8*>(&Bs[cur][(wn + j2*16)*32 + fro]);
    if (it + 1 < nk) stage((it + 1) << 5, cur ^ 1);
    BARX();
    LGKM0();
    __builtin_amdgcn_s_setprio(1);
#pragma unroll
    for (int i = 0; i < 4; i++)
#pragma unroll
      for (int j2 = 0; j2 < 4; j2++)
        acc[i][j2] = __builtin_amdgcn_mfma_f32_16x16x32_bf16(af[i], bfr[j2], acc[i][j2], 0, 0, 0);
    __builtin_amdgcn_s_setprio(0);
  }
  int rg = (lane >> 4) * 4, cq = lane & 15;
#pragma unroll
  for (int i = 0; i < 4; i++)
#pragma unroll
    for (int j2 = 0; j2 < 4; j2++) {
      size_t basei = (size_t)(m0 + wm + i*16 + rg) * N + (size_t)(n0 + wn + j2*16 + cq);
#pragma unroll
      for (int r = 0; r < 4; r++) {
        if constexpr (OUTF32) ((float*)Cv)[basei + (size_t)r * N] = acc[i][j2][r];
        else                  ((u16*)Cv)[basei + (size_t)r * N]   = f2bf(acc[i][j2][r]);
      }
    }
}

// ---------------- causal flash attention: R13 structure + raw v_exp ----------------
__global__ __launch_bounds__(192, 3) void attn_kernel(const u16* __restrict__ qkv, u16* __restrict__ attnout) {
  __shared__ u16 Sm[3][4096];    // per wave: K tile [0..2047], V^T tile [2048..4095]
  int tid = threadIdx.x;
  int w = tid >> 6, lane = tid & 63;
  int q31 = lane & 31, hi = lane >> 5;
  int lid = blockIdx.x;
  int xcd = lid & 7, j = lid >> 3;
  int bh = xcd * 4 + (j & 3);
  int p = j >> 2;                // 0..31 -> strips {63-p, p}
  int b = bh >> 4, h = bh & 15;
  const u16* base = qkv + (size_t)b * T_ * N1_;

  u16* Ks = Sm[w];
  u32* Vt32 = reinterpret_cast<u32*>(Sm[w] + 2048);

  const u16* ksrc = base + C_ + h*HD_ + (size_t)(lane >> 3) * N1_
                    + (size_t)(((lane & 7) ^ ((lane >> 3) & 7)) * 8);
  int kp2 = lane & 15, dc = (lane >> 4) * 16;
  int vcs = kp2 >> 2, vkl = kp2 & 3;
  int vflip = (lane >> 4) & 1;
  const u16* vsrc = base + 2*C_ + h*HD_ + (size_t)(2*kp2) * N1_ + dc;
  const float QSC = 0.125f * 1.44269504088896f;
  int swr = (q31 >> 1) & 3;
  int q31f = q31 ^ ((q31 >> 4) & 1);

  for (int sp = 0; sp < 2; sp++) {
    int strip = sp ? p : (63 - p);
    int qbase = strip * 32;
    int qg = qbase + q31;
    int nkt = strip + 1;

    f32x16 oacc[2] = {};
    float l_run = 0.f;

    if (w < nkt) {
      bf16x8 qf[4];
      {
        const u16* qrow = base + (size_t)qg * N1_ + h * HD_;
#pragma unroll
        for (int kk = 0; kk < 4; kk++) {
          bf16x8 raw = *reinterpret_cast<const bf16x8*>(qrow + kk*16 + hi*8);
          const u16* rp = (const u16*)&raw;
          u32x4 qp;
#pragma unroll
          for (int jj = 0; jj < 4; jj++)
            qp[jj] = cvtpk(bf2f(rp[2*jj]) * QSC, bf2f(rp[2*jj+1]) * QSC);
          qf[kk] = __builtin_bit_cast(bf16x8, qp);
        }
      }

      bf16x8 vA[2], vB[2];
      {
        size_t off0 = (size_t)(w * 32) * N1_;
#pragma unroll
        for (int r = 0; r < 4; r++)
          gload_lds16(ksrc + off0 + (size_t)(8*r) * N1_, (char*)Ks + r*1024);
#pragma unroll
        for (int r = 0; r < 2; r++) {
          vA[r] = *reinterpret_cast<const bf16x8*>(vsrc + off0 + r*8);
          vB[r] = *reinterpret_cast<const bf16x8*>(vsrc + off0 + r*8 + N1_);
        }
      }

      for (int kt = w; kt < nkt; kt += 3) {
        int kb = kt * 32;
        bool lastown  = (kt + 3 >= nkt);
        bool masktile = (kt == nkt - 1);

        asm volatile("s_waitcnt vmcnt(0)" ::: "memory");

        // early V write (PV reads ~500cyc later)
#pragma unroll
        for (int r2 = 0; r2 < 2; r2++) {
          const u16* au = (const u16*)&vA[r2];
          const u16* bu = (const u16*)&vB[r2];
#pragma unroll
          for (int i = 0; i < 8; i++) {
            int d = dc + r2*8 + i;
            Vt32[(d ^ vflip)*16 + ((vcs ^ ((d>>1)&3)) << 2) + vkl] = (u32)au[i] | ((u32)bu[i] << 16);
          }
        }

        f32x16 st = {};
#pragma unroll
        for (int kk = 0; kk < 4; kk++) {
          bf16x8 kf = *reinterpret_cast<const bf16x8*>(
              &Ks[q31*64 + ((((kk<<1) | hi) ^ (q31 & 7)) << 3)]);
          st = __builtin_amdgcn_mfma_f32_32x32x16_bf16(kf, qf[kk], st, 0, 0, 0);
        }
        asm volatile("s_waitcnt lgkmcnt(0)" ::: "memory");
        __builtin_amdgcn_sched_barrier(0);

        if (!lastown) {
          size_t off = (size_t)(kb + 96) * N1_;
#pragma unroll
          for (int r = 0; r < 4; r++)
            gload_lds16(ksrc + off + (size_t)(8*r) * N1_, (char*)Ks + r*1024);
#pragma unroll
          for (int r = 0; r < 2; r++) {
            vA[r] = *reinterpret_cast<const bf16x8*>(vsrc + off + r*8);
            vB[r] = *reinterpret_cast<const bf16x8*>(vsrc + off + r*8 + N1_);
          }
        }

        if (masktile) {
#pragma unroll
          for (int r = 0; r < 16; r++) {
            int keyg = kb + (r&3) + 8*(r>>2) + 4*hi;
            if (keyg > qg) st[r] = -__builtin_inff();
          }
        }
        float tsum = 0.f;
#pragma unroll
        for (int r = 0; r < 16; r++) {
          float pp = exp2v(st[r]);
          st[r] = pp;
          tsum += pp;
        }
        l_run += tsum;

        u32 pk[8];
#pragma unroll
        for (int m = 0; m < 8; m++) pk[m] = cvtpk(st[2*m], st[2*m+1]);
        asm volatile("v_permlane32_swap_b32 %0, %1" : "+v"(pk[0]), "+v"(pk[2]));
        asm volatile("v_permlane32_swap_b32 %0, %1" : "+v"(pk[1]), "+v"(pk[3]));
        asm volatile("v_permlane32_swap_b32 %0, %1" : "+v"(pk[4]), "+v"(pk[6]));
        asm volatile("v_permlane32_swap_b32 %0, %1" : "+v"(pk[5]), "+v"(pk[7]));
        u32x4 fr0 = { pk[0], pk[1], pk[2], pk[3] };
        u32x4 fr1 = { pk[4], pk[5], pk[6], pk[7] };
        bf16x8 pf0 = __builtin_bit_cast(bf16x8, fr0);
        bf16x8 pf1 = __builtin_bit_cast(bf16x8, fr1);

#pragma unroll
        for (int dt = 0; dt < 2; dt++)
#pragma unroll
          for (int kc = 0; kc < 2; kc++) {
            int cs = (kc << 1) | hi;
            bf16x8 vf = *reinterpret_cast<const bf16x8*>(
                &Vt32[(32*dt + q31f)*16 + ((cs ^ swr) << 2)]);
            oacc[dt] = __builtin_amdgcn_mfma_f32_32x32x16_bf16(vf, kc ? pf1 : pf0, oacc[dt], 0, 0, 0);
          }
      }
      l_run += __shfl_xor(l_run, 32);
    }

    __syncthreads();
    if (w) {
      float* park = (float*)Sm[w];
#pragma unroll
      for (int dt = 0; dt < 2; dt++)
#pragma unroll
        for (int r = 0; r < 16; r++) park[(dt*16 + r)*64 + lane] = oacc[dt][r];
      float* ml = (float*)Sm[0];
      ml[(w-1)*64 + lane] = l_run;
    }
    __syncthreads();
    if (w == 0) {
      const float* ml = (const float*)Sm[0];
      float linv = 1.f / (l_run + ml[lane] + ml[64 + lane]);
      const float* p1 = (const float*)Sm[1];
      const float* p2 = (const float*)Sm[2];
      u16* orow = attnout + (size_t)(b*T_ + qg) * C_ + h*HD_;
#pragma unroll
      for (int dt = 0; dt < 2; dt++)
#pragma unroll
        for (int m = 0; m < 8; m++) {
          int e0 = (dt*16 + 2*m)*64 + lane, e1 = e0 + 64;
          float v0 = (oacc[dt][2*m]   + p1[e0] + p2[e0]) * linv;
          float v1 = (oacc[dt][2*m+1] + p1[e1] + p2[e1]) * linv;
          int d = 32*dt + 2*(m&1) + 8*(m>>1) + 4*hi;
          *reinterpret_cast<u32*>(orow + d) = cvtpk(v0, v1);
        }
    }
    __syncthreads();
  }
}

extern "C" void kernel_launch(void* const* d_in, const int* in_sizes, int n_in,
                              void* d_out, int out_size, void* d_ws, size_t ws_size,
                              hipStream_t stream) {
  const float* x     = (const float*)d_in[0];
  const float* w_qkv = (const float*)d_in[1];
  const float* w_out = (const float*)d_in[2];
  float* out = (float*)d_out;
  char* ws = (char*)d_ws;
  u16* xb    = (u16*)(ws);                         // 8 MB  : x bf16 (4096 x 1024)
  u16* wqkvT = (u16*)(ws + ((size_t)8  << 20));    // 6 MB  : w_qkv^T bf16 (3072 x 1024)
  u16* woutT = (u16*)(ws + ((size_t)14 << 20));    // 2 MB  : w_out^T bf16 (1024 x 1024)
  u16* qkvb  = (u16*)(ws + ((size_t)16 << 20));    // 24 MB : qkv bf16 (4096 x 3072)
  u16* attnb = (u16*)(ws + ((size_t)40 << 20));    // 8 MB  : attn out bf16 (4096 x 1024)

  prep_k<<<8192, 256, 0, stream>>>(x, w_qkv, w_out, xb, wqkvT, woutT);
  gemm256<<<dim3(16, 16), 512, 0, stream>>>(xb, wqkvT, qkvb);
  attn_kernel<<<1024, 192, 0, stream>>>(qkvb, attnb);
  gemm_bt<1><<<dim3(C_/128, BT_/128), 256, 0, stream>>>(attnb, woutT, (void*)out, BT_, C_, C_);
}

// Round 20
// 112.312 us; speedup vs baseline: 1.2169x; 1.0115x over previous
//
#include <hip/hip_runtime.h>
#include <hip/hip_bf16.h>
#include <stdint.h>
#include <math.h>

#define B_ 2
#define T_ 2048
#define C_ 1024
#define H_ 16
#define HD_ 64
#define BT_ (B_*T_)      // 4096 rows
#define N1_ (3*C_)       // 3072

typedef unsigned short u16;
typedef uint32_t u32;
typedef __attribute__((ext_vector_type(8))) short bf16x8;
typedef __attribute__((ext_vector_type(4))) float f32x4;
typedef __attribute__((ext_vector_type(16))) float f32x16;
typedef __attribute__((ext_vector_type(4))) unsigned int u32x4;

__device__ __forceinline__ u16 f2bf(float f) {
  __hip_bfloat16 h = __float2bfloat16(f);
  return *reinterpret_cast<u16*>(&h);
}
__device__ __forceinline__ float bf2f(u16 u) {
  u32 w = ((u32)u) << 16;
  return *reinterpret_cast<float*>(&w);
}
__device__ __forceinline__ u32 cvtpk(float lo, float hi) {
  u32 r;
  asm("v_cvt_pk_bf16_f32 %0, %1, %2" : "=v"(r) : "v"(lo), "v"(hi));
  return r;
}
__device__ __forceinline__ float exp2v(float x) {   // exact v_exp_f32 (2^x); -inf -> 0
  float r;
  asm("v_exp_f32 %0, %1" : "=v"(r) : "v"(x));
  return r;
}

__device__ __forceinline__ void gload_lds16(const void* g, void* l) {
  __builtin_amdgcn_global_load_lds(
      (const __attribute__((address_space(1))) uint32_t*)g,
      (__attribute__((address_space(3))) uint32_t*)l, 16, 0, 0);
}

// raw workgroup barrier WITHOUT __syncthreads' vmcnt(0) drain
#define BARX() do { asm volatile("" ::: "memory"); __builtin_amdgcn_s_barrier(); \
                    asm volatile("" ::: "memory"); } while (0)
// lgkm drain + scheduler fence (rule #18)
#define LGKM0() do { asm volatile("s_waitcnt lgkmcnt(0)" ::: "memory"); \
                     __builtin_amdgcn_sched_barrier(0); } while (0)

// ---------------- fused prep: cast x + transpose-cast both weights ----------------
__global__ __launch_bounds__(256) void prep_k(const float* __restrict__ x,
                                              const float* __restrict__ w_qkv,
                                              const float* __restrict__ w_out,
                                              u16* __restrict__ xb,
                                              u16* __restrict__ wqkvT,
                                              u16* __restrict__ woutT) {
  __shared__ float tile[32][33];
  int bid = blockIdx.x;
  if (bid < 4096) {
    int idx = bid * 1024 + threadIdx.x * 4;
    float4 v = *reinterpret_cast<const float4*>(x + idx);
    u16 tmp[4] = {f2bf(v.x), f2bf(v.y), f2bf(v.z), f2bf(v.w)};
    *reinterpret_cast<uint2*>(xb + idx) = *reinterpret_cast<const uint2*>(tmp);
    return;
  }
  const float* w;
  u16* wt;
  int N, tb;
  if (bid < 7168) { tb = bid - 4096; w = w_qkv; wt = wqkvT; N = N1_; }
  else            { tb = bid - 7168; w = w_out; wt = woutT; N = C_;  }
  int nx = N >> 5;
  int n0 = (tb % nx) * 32, k0 = (tb / nx) * 32;
  int tx = threadIdx.x & 31, ty = threadIdx.x >> 5;
#pragma unroll
  for (int i = 0; i < 4; i++)
    tile[ty + i*8][tx] = w[(size_t)(k0 + ty + i*8) * N + n0 + tx];
  __syncthreads();
#pragma unroll
  for (int i = 0; i < 4; i++)
    wt[(size_t)(n0 + ty + i*8) * 1024 + k0 + tx] = f2bf(tile[tx][ty + i*8]);
}

// ---------------- QKV GEMM: 256x192, BK=64, 2-phase choreography (R19-proven) ----------------
__global__ __launch_bounds__(512, 2) void gemm256(const u16* __restrict__ A, const u16* __restrict__ Bt,
                                                  u16* __restrict__ Cc) {
  __shared__ u16 As[2][256*64];
  __shared__ u16 Bs[2][192*64];
  int tid = threadIdx.x, w = tid >> 6, lane = tid & 63;
  int m0 = blockIdx.y * 256, n0 = blockIdx.x * 192;
  int wm = (w >> 2) * 128, wn = (w & 3) * 48;
  f32x4 acc[8][3] = {};

  size_t aoff[4];
  size_t boff[3];
#pragma unroll
  for (int i = 0; i < 4; i++) {
    int c = i*512 + tid, row = c >> 3;
    aoff[i] = (size_t)(m0 + row) * 1024 + (size_t)((((c & 7) ^ (row & 7))) * 8);
  }
#pragma unroll
  for (int i = 0; i < 3; i++) {
    int c = i*512 + tid, row = c >> 3;
    boff[i] = (size_t)(n0 + row) * 1024 + (size_t)((((c & 7) ^ (row & 7))) * 8);
  }
  int dstc = w * 1024;

  int r15 = lane & 15, kq = lane >> 4;
  int slot0 = (kq ^ (r15 & 7)) * 8;
  int abase = (wm + r15) * 64;
  int bbase = (wn + r15) * 64;

#pragma unroll
  for (int i = 0; i < 4; i++)
    gload_lds16(A + aoff[i], (char*)&As[0][0] + i*8192 + dstc);
#pragma unroll
  for (int i = 0; i < 3; i++)
    gload_lds16(Bt + boff[i], (char*)&Bs[0][0] + i*8192 + dstc);

  for (int t = 0; t < 16; ++t) {
    int buf = t & 1;
    const u16* Ab = &As[buf][0];
    const u16* Bb = &Bs[buf][0];
    int slot1 = slot0 ^ 32;
    bf16x8 af[8], bfv[3];

    asm volatile("s_waitcnt vmcnt(0)" ::: "memory");
    BARX();

#pragma unroll
    for (int nf = 0; nf < 3; nf++) bfv[nf] = *reinterpret_cast<const bf16x8*>(&Bb[bbase + nf*1024 + slot0]);
#pragma unroll
    for (int mf = 0; mf < 8; mf++) af[mf] = *reinterpret_cast<const bf16x8*>(&Ab[abase + mf*1024 + slot0]);
    if (t < 15) {
      int ko = (t + 1) * 64;
#pragma unroll
      for (int i = 0; i < 4; i++)
        gload_lds16(A + aoff[i] + ko, (char*)&As[buf ^ 1][0] + i*8192 + dstc);
#pragma unroll
      for (int i = 0; i < 3; i++)
        gload_lds16(Bt + boff[i] + ko, (char*)&Bs[buf ^ 1][0] + i*8192 + dstc);
    }
    BARX();
    LGKM0();
    __builtin_amdgcn_s_setprio(1);
#pragma unroll
    for (int mf = 0; mf < 8; mf++)
#pragma unroll
      for (int nf = 0; nf < 3; nf++)
        acc[mf][nf] = __builtin_amdgcn_mfma_f32_16x16x32_bf16(af[mf], bfv[nf], acc[mf][nf], 0, 0, 0);
    __builtin_amdgcn_s_setprio(0);

#pragma unroll
    for (int nf = 0; nf < 3; nf++) bfv[nf] = *reinterpret_cast<const bf16x8*>(&Bb[bbase + nf*1024 + slot1]);
#pragma unroll
    for (int mf = 0; mf < 8; mf++) af[mf] = *reinterpret_cast<const bf16x8*>(&Ab[abase + mf*1024 + slot1]);
    BARX();
    LGKM0();
    __builtin_amdgcn_s_setprio(1);
#pragma unroll
    for (int mf = 0; mf < 8; mf++)
#pragma unroll
      for (int nf = 0; nf < 3; nf++)
        acc[mf][nf] = __builtin_amdgcn_mfma_f32_16x16x32_bf16(af[mf], bfv[nf], acc[mf][nf], 0, 0, 0);
    __builtin_amdgcn_s_setprio(0);
  }

  int rg = kq * 4;
#pragma unroll
  for (int mf = 0; mf < 8; mf++)
#pragma unroll
    for (int nf = 0; nf < 3; nf++) {
      size_t basei = (size_t)(m0 + wm + mf*16 + rg) * N1_ + (size_t)(n0 + wn + nf*16 + r15);
#pragma unroll
      for (int r = 0; r < 4; r++)
        Cc[basei + (size_t)r * N1_] = f2bf(acc[mf][nf][r]);
    }
}

// ---------------- out-proj GEMM (R18-proven) ----------------
template<int OUTF32>
__global__ __launch_bounds__(256) void gemm_bt(const u16* __restrict__ A, const u16* __restrict__ Bt,
                                               void* __restrict__ Cv, int M, int N, int K) {
  __shared__ u16 As[2][128*32];
  __shared__ u16 Bs[2][128*32];
  int tid = threadIdx.x, wave = tid >> 6, lane = tid & 63;
  int m0 = blockIdx.y * 128, n0 = blockIdx.x * 128;
  int wm = (wave >> 1) * 64, wn = (wave & 1) * 64;
  f32x4 acc[4][4] = {};
  int srow = lane >> 2, scol = (lane & 3) * 8;
  int fro  = (lane & 15) * 32 + (lane >> 4) * 8;

  auto stage = [&](int k0, int buf) {
#pragma unroll
    for (int i = 0; i < 2; i++) {
      gload_lds16(A  + (size_t)(m0 + i*64 + wave*16 + srow) * K + k0 + scol, &As[buf][(i*64 + wave*16) * 32]);
      gload_lds16(Bt + (size_t)(n0 + i*64 + wave*16 + srow) * K + k0 + scol, &Bs[buf][(i*64 + wave*16) * 32]);
    }
  };

  stage(0, 0);
  int nk = K >> 5;
  for (int it = 0; it < nk; ++it) {
    int cur = it & 1;
    asm volatile("s_waitcnt vmcnt(0)" ::: "memory");
    BARX();
    bf16x8 af[4], bfr[4];
#pragma unroll
    for (int i = 0; i < 4; i++) af[i]  = *reinterpret_cast<const bf16x8*>(&As[cur][(wm + i*16)*32 + fro]);
#pragma unroll
    for (int j2 = 0; j2 < 4; j2++) bfr[j2] = *reinterpret_cast<const bf16x8*>(&Bs[cur][(wn + j2*16)*32 + fro]);
    if (it + 1 < nk) stage((it + 1) << 5, cur ^ 1);
    BARX();
    LGKM0();
    __builtin_amdgcn_s_setprio(1);
#pragma unroll
    for (int i = 0; i < 4; i++)
#pragma unroll
      for (int j2 = 0; j2 < 4; j2++)
        acc[i][j2] = __builtin_amdgcn_mfma_f32_16x16x32_bf16(af[i], bfr[j2], acc[i][j2], 0, 0, 0);
    __builtin_amdgcn_s_setprio(0);
  }
  int rg = (lane >> 4) * 4, cq = lane & 15;
#pragma unroll
  for (int i = 0; i < 4; i++)
#pragma unroll
    for (int j2 = 0; j2 < 4; j2++) {
      size_t basei = (size_t)(m0 + wm + i*16 + rg) * N + (size_t)(n0 + wn + j2*16 + cq);
#pragma unroll
      for (int r = 0; r < 4; r++) {
        if constexpr (OUTF32) ((float*)Cv)[basei + (size_t)r * N] = acc[i][j2][r];
        else                  ((u16*)Cv)[basei + (size_t)r * N]   = f2bf(acc[i][j2][r]);
      }
    }
}

// ---------------- causal flash attention: dual-strip shared-K/V pass ----------------
// 1024 blocks x 192 thr (3 waves, 3-way key-split). Block owns strips A=63-p, B=p
// processed TOGETHER over the union tiles 0..sA (B active for kt<=sB): per tile,
// kf/vf fragments are read ONCE and fire MFMAs for both strips. Tile-visits per
// block: 65 -> 64-p (mean 48.5); K/V global fetch halved on overlap. Compute per
// block constant (65 tile-computes) -> balance preserved. Two sequential 3-way
// merges at the end. Per-tile body otherwise R13/R19-proven.
__global__ __launch_bounds__(192, 3) void attn_kernel(const u16* __restrict__ qkv, u16* __restrict__ attnout) {
  __shared__ u16 Sm[3][4096];    // per wave: K tile [0..2047], V^T tile [2048..4095]
  int tid = threadIdx.x;
  int w = tid >> 6, lane = tid & 63;
  int q31 = lane & 31, hi = lane >> 5;
  int lid = blockIdx.x;
  int xcd = lid & 7, j = lid >> 3;
  int bh = xcd * 4 + (j & 3);
  int p = j >> 2;                // 0..31
  int b = bh >> 4, h = bh & 15;
  const u16* base = qkv + (size_t)b * T_ * N1_;

  u16* Ks = Sm[w];
  u32* Vt32 = reinterpret_cast<u32*>(Sm[w] + 2048);

  const u16* ksrc = base + C_ + h*HD_ + (size_t)(lane >> 3) * N1_
                    + (size_t)(((lane & 7) ^ ((lane >> 3) & 7)) * 8);
  int kp2 = lane & 15, dc = (lane >> 4) * 16;
  int vcs = kp2 >> 2, vkl = kp2 & 3;
  int vflip = (lane >> 4) & 1;
  const u16* vsrc = base + 2*C_ + h*HD_ + (size_t)(2*kp2) * N1_ + dc;
  const float QSC = 0.125f * 1.44269504088896f;
  int swr = (q31 >> 1) & 3;
  int q31f = q31 ^ ((q31 >> 4) & 1);

  int sA = 63 - p, sB = p;
  int qgA = sA * 32 + q31, qgB = sB * 32 + q31;
  int nktU = sA + 1;             // union tiles (>=33, so all 3 waves active)

  // Q fragments for both strips, pre-scaled into exp2 domain
  bf16x8 qfA[4], qfB[4];
  {
    const u16* qrowA = base + (size_t)qgA * N1_ + h * HD_;
    const u16* qrowB = base + (size_t)qgB * N1_ + h * HD_;
#pragma unroll
    for (int kk = 0; kk < 4; kk++) {
      bf16x8 ra = *reinterpret_cast<const bf16x8*>(qrowA + kk*16 + hi*8);
      bf16x8 rb = *reinterpret_cast<const bf16x8*>(qrowB + kk*16 + hi*8);
      const u16* pa = (const u16*)&ra;
      const u16* pb = (const u16*)&rb;
      u32x4 qa, qb;
#pragma unroll
      for (int jj = 0; jj < 4; jj++) {
        qa[jj] = cvtpk(bf2f(pa[2*jj]) * QSC, bf2f(pa[2*jj+1]) * QSC);
        qb[jj] = cvtpk(bf2f(pb[2*jj]) * QSC, bf2f(pb[2*jj+1]) * QSC);
      }
      qfA[kk] = __builtin_bit_cast(bf16x8, qa);
      qfB[kk] = __builtin_bit_cast(bf16x8, qb);
    }
  }

  f32x16 oaccA[2] = {}, oaccB[2] = {};
  float lA = 0.f, lB = 0.f;

  bf16x8 vA[2], vB[2];
  // ---- prologue: stage own first tile kt=w ----
  {
    size_t off0 = (size_t)(w * 32) * N1_;
#pragma unroll
    for (int r = 0; r < 4; r++)
      gload_lds16(ksrc + off0 + (size_t)(8*r) * N1_, (char*)Ks + r*1024);
#pragma unroll
    for (int r = 0; r < 2; r++) {
      vA[r] = *reinterpret_cast<const bf16x8*>(vsrc + off0 + r*8);
      vB[r] = *reinterpret_cast<const bf16x8*>(vsrc + off0 + r*8 + N1_);
    }
  }

  for (int kt = w; kt < nktU; kt += 3) {
    int kb = kt * 32;
    bool lastown = (kt + 3 >= nktU);
    bool actB = (kt <= sB);

    asm volatile("s_waitcnt vmcnt(0)" ::: "memory");

    // ---- early V write (PV reads ~500cyc later) ----
#pragma unroll
    for (int r2 = 0; r2 < 2; r2++) {
      const u16* au = (const u16*)&vA[r2];
      const u16* bu = (const u16*)&vB[r2];
#pragma unroll
      for (int i = 0; i < 8; i++) {
        int d = dc + r2*8 + i;
        Vt32[(d ^ vflip)*16 + ((vcs ^ ((d>>1)&3)) << 2) + vkl] = (u32)au[i] | ((u32)bu[i] << 16);
      }
    }

    // ---- QK^T for both strips, kf read once ----
    f32x16 stA = {}, stB = {};
    if (actB) {
#pragma unroll
      for (int kk = 0; kk < 4; kk++) {
        bf16x8 kf = *reinterpret_cast<const bf16x8*>(
            &Ks[q31*64 + ((((kk<<1) | hi) ^ (q31 & 7)) << 3)]);
        stA = __builtin_amdgcn_mfma_f32_32x32x16_bf16(kf, qfA[kk], stA, 0, 0, 0);
        stB = __builtin_amdgcn_mfma_f32_32x32x16_bf16(kf, qfB[kk], stB, 0, 0, 0);
      }
    } else {
#pragma unroll
      for (int kk = 0; kk < 4; kk++) {
        bf16x8 kf = *reinterpret_cast<const bf16x8*>(
            &Ks[q31*64 + ((((kk<<1) | hi) ^ (q31 & 7)) << 3)]);
        stA = __builtin_amdgcn_mfma_f32_32x32x16_bf16(kf, qfA[kk], stA, 0, 0, 0);
      }
    }
    asm volatile("s_waitcnt lgkmcnt(0)" ::: "memory");
    __builtin_amdgcn_sched_barrier(0);

    // ---- prefetch own next tile ----
    if (!lastown) {
      size_t off = (size_t)(kb + 96) * N1_;
#pragma unroll
      for (int r = 0; r < 4; r++)
        gload_lds16(ksrc + off + (size_t)(8*r) * N1_, (char*)Ks + r*1024);
#pragma unroll
      for (int r = 0; r < 2; r++) {
        vA[r] = *reinterpret_cast<const bf16x8*>(vsrc + off + r*8);
        vB[r] = *reinterpret_cast<const bf16x8*>(vsrc + off + r*8 + N1_);
      }
    }

    // ---- softmax + pack A ----
    if (kt == sA) {
#pragma unroll
      for (int r = 0; r < 16; r++) {
        int keyg = kb + (r&3) + 8*(r>>2) + 4*hi;
        if (keyg > qgA) stA[r] = -__builtin_inff();
      }
    }
    {
      float ts = 0.f;
#pragma unroll
      for (int r = 0; r < 16; r++) {
        float pp = exp2v(stA[r]);
        stA[r] = pp;
        ts += pp;
      }
      lA += ts;
    }
    bf16x8 pfA0, pfA1;
    {
      u32 pk[8];
#pragma unroll
      for (int m = 0; m < 8; m++) pk[m] = cvtpk(stA[2*m], stA[2*m+1]);
      asm volatile("v_permlane32_swap_b32 %0, %1" : "+v"(pk[0]), "+v"(pk[2]));
      asm volatile("v_permlane32_swap_b32 %0, %1" : "+v"(pk[1]), "+v"(pk[3]));
      asm volatile("v_permlane32_swap_b32 %0, %1" : "+v"(pk[4]), "+v"(pk[6]));
      asm volatile("v_permlane32_swap_b32 %0, %1" : "+v"(pk[5]), "+v"(pk[7]));
      u32x4 f0 = { pk[0], pk[1], pk[2], pk[3] };
      u32x4 f1 = { pk[4], pk[5], pk[6], pk[7] };
      pfA0 = __builtin_bit_cast(bf16x8, f0);
      pfA1 = __builtin_bit_cast(bf16x8, f1);
    }

    if (actB) {
      // ---- softmax + pack B ----
      if (kt == sB) {
#pragma unroll
        for (int r = 0; r < 16; r++) {
          int keyg = kb + (r&3) + 8*(r>>2) + 4*hi;
          if (keyg > qgB) stB[r] = -__builtin_inff();
        }
      }
      {
        float ts = 0.f;
#pragma unroll
        for (int r = 0; r < 16; r++) {
          float pp = exp2v(stB[r]);
          stB[r] = pp;
          ts += pp;
        }
        lB += ts;
      }
      bf16x8 pfB0, pfB1;
      {
        u32 pk[8];
#pragma unroll
        for (int m = 0; m < 8; m++) pk[m] = cvtpk(stB[2*m], stB[2*m+1]);
        asm volatile("v_permlane32_swap_b32 %0, %1" : "+v"(pk[0]), "+v"(pk[2]));
        asm volatile("v_permlane32_swap_b32 %0, %1" : "+v"(pk[1]), "+v"(pk[3]));
        asm volatile("v_permlane32_swap_b32 %0, %1" : "+v"(pk[4]), "+v"(pk[6]));
        asm volatile("v_permlane32_swap_b32 %0, %1" : "+v"(pk[5]), "+v"(pk[7]));
        u32x4 f0 = { pk[0], pk[1], pk[2], pk[3] };
        u32x4 f1 = { pk[4], pk[5], pk[6], pk[7] };
        pfB0 = __builtin_bit_cast(bf16x8, f0);
        pfB1 = __builtin_bit_cast(bf16x8, f1);
      }
      // ---- PV both strips, vf read once ----
#pragma unroll
      for (int dt = 0; dt < 2; dt++)
#pragma unroll
        for (int kc = 0; kc < 2; kc++) {
          int cs = (kc << 1) | hi;
          bf16x8 vf = *reinterpret_cast<const bf16x8*>(
              &Vt32[(32*dt + q31f)*16 + ((cs ^ swr) << 2)]);
          oaccA[dt] = __builtin_amdgcn_mfma_f32_32x32x16_bf16(vf, kc ? pfA1 : pfA0, oaccA[dt], 0, 0, 0);
          oaccB[dt] = __builtin_amdgcn_mfma_f32_32x32x16_bf16(vf, kc ? pfB1 : pfB0, oaccB[dt], 0, 0, 0);
        }
    } else {
      // ---- PV strip A only ----
#pragma unroll
      for (int dt = 0; dt < 2; dt++)
#pragma unroll
        for (int kc = 0; kc < 2; kc++) {
          int cs = (kc << 1) | hi;
          bf16x8 vf = *reinterpret_cast<const bf16x8*>(
              &Vt32[(32*dt + q31f)*16 + ((cs ^ swr) << 2)]);
          oaccA[dt] = __builtin_amdgcn_mfma_f32_32x32x16_bf16(vf, kc ? pfA1 : pfA0, oaccA[dt], 0, 0, 0);
        }
    }
  }
  lA += __shfl_xor(lA, 32);
  lB += __shfl_xor(lB, 32);

  // ---- merge strip A ----
  __syncthreads();
  if (w) {
    float* park = (float*)Sm[w];
#pragma unroll
    for (int dt = 0; dt < 2; dt++)
#pragma unroll
      for (int r = 0; r < 16; r++) park[(dt*16 + r)*64 + lane] = oaccA[dt][r];
    float* ml = (float*)Sm[0];
    ml[(w-1)*64 + lane] = lA;
  }
  __syncthreads();
  if (w == 0) {
    const float* ml = (const float*)Sm[0];
    float linv = 1.f / (lA + ml[lane] + ml[64 + lane]);
    const float* p1 = (const float*)Sm[1];
    const float* p2 = (const float*)Sm[2];
    u16* orow = attnout + (size_t)(b*T_ + qgA) * C_ + h*HD_;
#pragma unroll
    for (int dt = 0; dt < 2; dt++)
#pragma unroll
      for (int m = 0; m < 8; m++) {
        int e0 = (dt*16 + 2*m)*64 + lane, e1 = e0 + 64;
        float v0 = (oaccA[dt][2*m]   + p1[e0] + p2[e0]) * linv;
        float v1 = (oaccA[dt][2*m+1] + p1[e1] + p2[e1]) * linv;
        int d = 32*dt + 2*(m&1) + 8*(m>>1) + 4*hi;
        *reinterpret_cast<u32*>(orow + d) = cvtpk(v0, v1);
      }
  }
  __syncthreads();
  // ---- merge strip B ----
  if (w) {
    float* park = (float*)Sm[w];
#pragma unroll
    for (int dt = 0; dt < 2; dt++)
#pragma unroll
      for (int r = 0; r < 16; r++) park[(dt*16 + r)*64 + lane] = oaccB[dt][r];
    float* ml = (float*)Sm[0];
    ml[(w-1)*64 + lane] = lB;
  }
  __syncthreads();
  if (w == 0) {
    const float* ml = (const float*)Sm[0];
    float linv = 1.f / (lB + ml[lane] + ml[64 + lane]);
    const float* p1 = (const float*)Sm[1];
    const float* p2 = (const float*)Sm[2];
    u16* orow = attnout + (size_t)(b*T_ + qgB) * C_ + h*HD_;
#pragma unroll
    for (int dt = 0; dt < 2; dt++)
#pragma unroll
      for (int m = 0; m < 8; m++) {
        int e0 = (dt*16 + 2*m)*64 + lane, e1 = e0 + 64;
        float v0 = (oaccB[dt][2*m]   + p1[e0] + p2[e0]) * linv;
        float v1 = (oaccB[dt][2*m+1] + p1[e1] + p2[e1]) * linv;
        int d = 32*dt + 2*(m&1) + 8*(m>>1) + 4*hi;
        *reinterpret_cast<u32*>(orow + d) = cvtpk(v0, v1);
      }
  }
}

extern "C" void kernel_launch(void* const* d_in, const int* in_sizes, int n_in,
                              void* d_out, int out_size, void* d_ws, size_t ws_size,
                              hipStream_t stream) {
  const float* x     = (const float*)d_in[0];
  const float* w_qkv = (const float*)d_in[1];
  const float* w_out = (const float*)d_in[2];
  float* out = (float*)d_out;
  char* ws = (char*)d_ws;
  u16* xb    = (u16*)(ws);                         // 8 MB  : x bf16 (4096 x 1024)
  u16* wqkvT = (u16*)(ws + ((size_t)8  << 20));    // 6 MB  : w_qkv^T bf16 (3072 x 1024)
  u16* woutT = (u16*)(ws + ((size_t)14 << 20));    // 2 MB  : w_out^T bf16 (1024 x 1024)
  u16* qkvb  = (u16*)(ws + ((size_t)16 << 20));    // 24 MB : qkv bf16 (4096 x 3072)
  u16* attnb = (u16*)(ws + ((size_t)40 << 20));    // 8 MB  : attn out bf16 (4096 x 1024)

  prep_k<<<8192, 256, 0, stream>>>(x, w_qkv, w_out, xb, wqkvT, woutT);
  gemm256<<<dim3(16, 16), 512, 0, stream>>>(xb, wqkvT, qkvb);
  attn_kernel<<<1024, 192, 0, stream>>>(qkvb, attnb);
  gemm_bt<1><<<dim3(C_/128, BT_/128), 256, 0, stream>>>(attnb, woutT, (void*)out, BT_, C_, C_);
}

// Round 21
// 102.928 us; speedup vs baseline: 1.3279x; 1.0912x over previous
//
#include <hip/hip_runtime.h>
#include <hip/hip_bf16.h>
#include <stdint.h>
#include <math.h>

#define B_ 2
#define T_ 2048
#define C_ 1024
#define H_ 16
#define HD_ 64
#define BT_ (B_*T_)      // 4096 rows
#define N1_ (3*C_)       // 3072

typedef unsigned short u16;
typedef uint32_t u32;
typedef __attribute__((ext_vector_type(8))) short bf16x8;
typedef __attribute__((ext_vector_type(4))) float f32x4;
typedef __attribute__((ext_vector_type(16))) float f32x16;
typedef __attribute__((ext_vector_type(4))) unsigned int u32x4;

__device__ __forceinline__ u16 f2bf(float f) {
  __hip_bfloat16 h = __float2bfloat16(f);
  return *reinterpret_cast<u16*>(&h);
}
__device__ __forceinline__ float bf2f(u16 u) {
  u32 w = ((u32)u) << 16;
  return *reinterpret_cast<float*>(&w);
}
__device__ __forceinline__ u32 cvtpk(float lo, float hi) {
  u32 r;
  asm("v_cvt_pk_bf16_f32 %0, %1, %2" : "=v"(r) : "v"(lo), "v"(hi));
  return r;
}
__device__ __forceinline__ float exp2v(float x) {   // exact v_exp_f32 (2^x); -inf -> 0
  float r;
  asm("v_exp_f32 %0, %1" : "=v"(r) : "v"(x));
  return r;
}

__device__ __forceinline__ void gload_lds16(const void* g, void* l) {
  __builtin_amdgcn_global_load_lds(
      (const __attribute__((address_space(1))) uint32_t*)g,
      (__attribute__((address_space(3))) uint32_t*)l, 16, 0, 0);
}

// raw workgroup barrier WITHOUT __syncthreads' vmcnt(0) drain
#define BARX() do { asm volatile("" ::: "memory"); __builtin_amdgcn_s_barrier(); \
                    asm volatile("" ::: "memory"); } while (0)
// lgkm drain + scheduler fence (rule #18)
#define LGKM0() do { asm volatile("s_waitcnt lgkmcnt(0)" ::: "memory"); \
                     __builtin_amdgcn_sched_barrier(0); } while (0)

// ---------------- fused prep: cast x + transpose-cast both weights ----------------
__global__ __launch_bounds__(256) void prep_k(const float* __restrict__ x,
                                              const float* __restrict__ w_qkv,
                                              const float* __restrict__ w_out,
                                              u16* __restrict__ xb,
                                              u16* __restrict__ wqkvT,
                                              u16* __restrict__ woutT) {
  __shared__ float tile[32][33];
  int bid = blockIdx.x;
  if (bid < 4096) {
    int idx = bid * 1024 + threadIdx.x * 4;
    float4 v = *reinterpret_cast<const float4*>(x + idx);
    u16 tmp[4] = {f2bf(v.x), f2bf(v.y), f2bf(v.z), f2bf(v.w)};
    *reinterpret_cast<uint2*>(xb + idx) = *reinterpret_cast<const uint2*>(tmp);
    return;
  }
  const float* w;
  u16* wt;
  int N, tb;
  if (bid < 7168) { tb = bid - 4096; w = w_qkv; wt = wqkvT; N = N1_; }
  else            { tb = bid - 7168; w = w_out; wt = woutT; N = C_;  }
  int nx = N >> 5;
  int n0 = (tb % nx) * 32, k0 = (tb / nx) * 32;
  int tx = threadIdx.x & 31, ty = threadIdx.x >> 5;
#pragma unroll
  for (int i = 0; i < 4; i++)
    tile[ty + i*8][tx] = w[(size_t)(k0 + ty + i*8) * N + n0 + tx];
  __syncthreads();
#pragma unroll
  for (int i = 0; i < 4; i++)
    wt[(size_t)(n0 + ty + i*8) * 1024 + k0 + tx] = f2bf(tile[tx][ty + i*8]);
}

// ---------------- QKV GEMM: 256x192, BK=64, 2-phase choreography (R19-proven) ----------------
__global__ __launch_bounds__(512, 2) void gemm256(const u16* __restrict__ A, const u16* __restrict__ Bt,
                                                  u16* __restrict__ Cc) {
  __shared__ u16 As[2][256*64];
  __shared__ u16 Bs[2][192*64];
  int tid = threadIdx.x, w = tid >> 6, lane = tid & 63;
  int m0 = blockIdx.y * 256, n0 = blockIdx.x * 192;
  int wm = (w >> 2) * 128, wn = (w & 3) * 48;
  f32x4 acc[8][3] = {};

  size_t aoff[4];
  size_t boff[3];
#pragma unroll
  for (int i = 0; i < 4; i++) {
    int c = i*512 + tid, row = c >> 3;
    aoff[i] = (size_t)(m0 + row) * 1024 + (size_t)((((c & 7) ^ (row & 7))) * 8);
  }
#pragma unroll
  for (int i = 0; i < 3; i++) {
    int c = i*512 + tid, row = c >> 3;
    boff[i] = (size_t)(n0 + row) * 1024 + (size_t)((((c & 7) ^ (row & 7))) * 8);
  }
  int dstc = w * 1024;

  int r15 = lane & 15, kq = lane >> 4;
  int slot0 = (kq ^ (r15 & 7)) * 8;
  int abase = (wm + r15) * 64;
  int bbase = (wn + r15) * 64;

#pragma unroll
  for (int i = 0; i < 4; i++)
    gload_lds16(A + aoff[i], (char*)&As[0][0] + i*8192 + dstc);
#pragma unroll
  for (int i = 0; i < 3; i++)
    gload_lds16(Bt + boff[i], (char*)&Bs[0][0] + i*8192 + dstc);

  for (int t = 0; t < 16; ++t) {
    int buf = t & 1;
    const u16* Ab = &As[buf][0];
    const u16* Bb = &Bs[buf][0];
    int slot1 = slot0 ^ 32;
    bf16x8 af[8], bfv[3];

    asm volatile("s_waitcnt vmcnt(0)" ::: "memory");
    BARX();

#pragma unroll
    for (int nf = 0; nf < 3; nf++) bfv[nf] = *reinterpret_cast<const bf16x8*>(&Bb[bbase + nf*1024 + slot0]);
#pragma unroll
    for (int mf = 0; mf < 8; mf++) af[mf] = *reinterpret_cast<const bf16x8*>(&Ab[abase + mf*1024 + slot0]);
    if (t < 15) {
      int ko = (t + 1) * 64;
#pragma unroll
      for (int i = 0; i < 4; i++)
        gload_lds16(A + aoff[i] + ko, (char*)&As[buf ^ 1][0] + i*8192 + dstc);
#pragma unroll
      for (int i = 0; i < 3; i++)
        gload_lds16(Bt + boff[i] + ko, (char*)&Bs[buf ^ 1][0] + i*8192 + dstc);
    }
    BARX();
    LGKM0();
    __builtin_amdgcn_s_setprio(1);
#pragma unroll
    for (int mf = 0; mf < 8; mf++)
#pragma unroll
      for (int nf = 0; nf < 3; nf++)
        acc[mf][nf] = __builtin_amdgcn_mfma_f32_16x16x32_bf16(af[mf], bfv[nf], acc[mf][nf], 0, 0, 0);
    __builtin_amdgcn_s_setprio(0);

#pragma unroll
    for (int nf = 0; nf < 3; nf++) bfv[nf] = *reinterpret_cast<const bf16x8*>(&Bb[bbase + nf*1024 + slot1]);
#pragma unroll
    for (int mf = 0; mf < 8; mf++) af[mf] = *reinterpret_cast<const bf16x8*>(&Ab[abase + mf*1024 + slot1]);
    BARX();
    LGKM0();
    __builtin_amdgcn_s_setprio(1);
#pragma unroll
    for (int mf = 0; mf < 8; mf++)
#pragma unroll
      for (int nf = 0; nf < 3; nf++)
        acc[mf][nf] = __builtin_amdgcn_mfma_f32_16x16x32_bf16(af[mf], bfv[nf], acc[mf][nf], 0, 0, 0);
    __builtin_amdgcn_s_setprio(0);
  }

  int rg = kq * 4;
#pragma unroll
  for (int mf = 0; mf < 8; mf++)
#pragma unroll
    for (int nf = 0; nf < 3; nf++) {
      size_t basei = (size_t)(m0 + wm + mf*16 + rg) * N1_ + (size_t)(n0 + wn + nf*16 + r15);
#pragma unroll
      for (int r = 0; r < 4; r++)
        Cc[basei + (size_t)r * N1_] = f2bf(acc[mf][nf][r]);
    }
}

// ---------------- out-proj GEMM (R18-proven) ----------------
template<int OUTF32>
__global__ __launch_bounds__(256) void gemm_bt(const u16* __restrict__ A, const u16* __restrict__ Bt,
                                               void* __restrict__ Cv, int M, int N, int K) {
  __shared__ u16 As[2][128*32];
  __shared__ u16 Bs[2][128*32];
  int tid = threadIdx.x, wave = tid >> 6, lane = tid & 63;
  int m0 = blockIdx.y * 128, n0 = blockIdx.x * 128;
  int wm = (wave >> 1) * 64, wn = (wave & 1) * 64;
  f32x4 acc[4][4] = {};
  int srow = lane >> 2, scol = (lane & 3) * 8;
  int fro  = (lane & 15) * 32 + (lane >> 4) * 8;

  auto stage = [&](int k0, int buf) {
#pragma unroll
    for (int i = 0; i < 2; i++) {
      gload_lds16(A  + (size_t)(m0 + i*64 + wave*16 + srow) * K + k0 + scol, &As[buf][(i*64 + wave*16) * 32]);
      gload_lds16(Bt + (size_t)(n0 + i*64 + wave*16 + srow) * K + k0 + scol, &Bs[buf][(i*64 + wave*16) * 32]);
    }
  };

  stage(0, 0);
  int nk = K >> 5;
  for (int it = 0; it < nk; ++it) {
    int cur = it & 1;
    asm volatile("s_waitcnt vmcnt(0)" ::: "memory");
    BARX();
    bf16x8 af[4], bfr[4];
#pragma unroll
    for (int i = 0; i < 4; i++) af[i]  = *reinterpret_cast<const bf16x8*>(&As[cur][(wm + i*16)*32 + fro]);
#pragma unroll
    for (int j2 = 0; j2 < 4; j2++) bfr[j2] = *reinterpret_cast<const bf16x8*>(&Bs[cur][(wn + j2*16)*32 + fro]);
    if (it + 1 < nk) stage((it + 1) << 5, cur ^ 1);
    BARX();
    LGKM0();
    __builtin_amdgcn_s_setprio(1);
#pragma unroll
    for (int i = 0; i < 4; i++)
#pragma unroll
      for (int j2 = 0; j2 < 4; j2++)
        acc[i][j2] = __builtin_amdgcn_mfma_f32_16x16x32_bf16(af[i], bfr[j2], acc[i][j2], 0, 0, 0);
    __builtin_amdgcn_s_setprio(0);
  }
  int rg = (lane >> 4) * 4, cq = lane & 15;
#pragma unroll
  for (int i = 0; i < 4; i++)
#pragma unroll
    for (int j2 = 0; j2 < 4; j2++) {
      size_t basei = (size_t)(m0 + wm + i*16 + rg) * N + (size_t)(n0 + wn + j2*16 + cq);
#pragma unroll
      for (int r = 0; r < 4; r++) {
        if constexpr (OUTF32) ((float*)Cv)[basei + (size_t)r * N] = acc[i][j2][r];
        else                  ((u16*)Cv)[basei + (size_t)r * N]   = f2bf(acc[i][j2][r]);
      }
    }
}

// ---------------- causal flash attention: dual-strip shared-K/V, NO-SPILL sizing ----------------
// R20 structure (dual-strip union pass, proven +4us despite spilling) at
// launch_bounds(192,2): VGPR cap 256 >= ~200 demand -> no scratch round-trip
// (R20 spilled 14MB at the (192,3) 170-cap). Occupancy 12 -> 8 waves/CU; spill
// arithmetic (21MB traffic ~ 30us) predicts net win.
__global__ __launch_bounds__(192, 2) void attn_kernel(const u16* __restrict__ qkv, u16* __restrict__ attnout) {
  __shared__ u16 Sm[3][4096];    // per wave: K tile [0..2047], V^T tile [2048..4095]
  int tid = threadIdx.x;
  int w = tid >> 6, lane = tid & 63;
  int q31 = lane & 31, hi = lane >> 5;
  int lid = blockIdx.x;
  int xcd = lid & 7, j = lid >> 3;
  int bh = xcd * 4 + (j & 3);
  int p = j >> 2;                // 0..31
  int b = bh >> 4, h = bh & 15;
  const u16* base = qkv + (size_t)b * T_ * N1_;

  u16* Ks = Sm[w];
  u32* Vt32 = reinterpret_cast<u32*>(Sm[w] + 2048);

  const u16* ksrc = base + C_ + h*HD_ + (size_t)(lane >> 3) * N1_
                    + (size_t)(((lane & 7) ^ ((lane >> 3) & 7)) * 8);
  int kp2 = lane & 15, dc = (lane >> 4) * 16;
  int vcs = kp2 >> 2, vkl = kp2 & 3;
  int vflip = (lane >> 4) & 1;
  const u16* vsrc = base + 2*C_ + h*HD_ + (size_t)(2*kp2) * N1_ + dc;
  const float QSC = 0.125f * 1.44269504088896f;
  int swr = (q31 >> 1) & 3;
  int q31f = q31 ^ ((q31 >> 4) & 1);

  int sA = 63 - p, sB = p;
  int qgA = sA * 32 + q31, qgB = sB * 32 + q31;
  int nktU = sA + 1;             // union tiles (>=33, so all 3 waves active)

  // Q fragments for both strips, pre-scaled into exp2 domain
  bf16x8 qfA[4], qfB[4];
  {
    const u16* qrowA = base + (size_t)qgA * N1_ + h * HD_;
    const u16* qrowB = base + (size_t)qgB * N1_ + h * HD_;
#pragma unroll
    for (int kk = 0; kk < 4; kk++) {
      bf16x8 ra = *reinterpret_cast<const bf16x8*>(qrowA + kk*16 + hi*8);
      bf16x8 rb = *reinterpret_cast<const bf16x8*>(qrowB + kk*16 + hi*8);
      const u16* pa = (const u16*)&ra;
      const u16* pb = (const u16*)&rb;
      u32x4 qa, qb;
#pragma unroll
      for (int jj = 0; jj < 4; jj++) {
        qa[jj] = cvtpk(bf2f(pa[2*jj]) * QSC, bf2f(pa[2*jj+1]) * QSC);
        qb[jj] = cvtpk(bf2f(pb[2*jj]) * QSC, bf2f(pb[2*jj+1]) * QSC);
      }
      qfA[kk] = __builtin_bit_cast(bf16x8, qa);
      qfB[kk] = __builtin_bit_cast(bf16x8, qb);
    }
  }

  f32x16 oaccA[2] = {}, oaccB[2] = {};
  float lA = 0.f, lB = 0.f;

  bf16x8 vA[2], vB[2];
  // ---- prologue: stage own first tile kt=w ----
  {
    size_t off0 = (size_t)(w * 32) * N1_;
#pragma unroll
    for (int r = 0; r < 4; r++)
      gload_lds16(ksrc + off0 + (size_t)(8*r) * N1_, (char*)Ks + r*1024);
#pragma unroll
    for (int r = 0; r < 2; r++) {
      vA[r] = *reinterpret_cast<const bf16x8*>(vsrc + off0 + r*8);
      vB[r] = *reinterpret_cast<const bf16x8*>(vsrc + off0 + r*8 + N1_);
    }
  }

  for (int kt = w; kt < nktU; kt += 3) {
    int kb = kt * 32;
    bool lastown = (kt + 3 >= nktU);
    bool actB = (kt <= sB);

    asm volatile("s_waitcnt vmcnt(0)" ::: "memory");

    // ---- early V write (PV reads ~500cyc later) ----
#pragma unroll
    for (int r2 = 0; r2 < 2; r2++) {
      const u16* au = (const u16*)&vA[r2];
      const u16* bu = (const u16*)&vB[r2];
#pragma unroll
      for (int i = 0; i < 8; i++) {
        int d = dc + r2*8 + i;
        Vt32[(d ^ vflip)*16 + ((vcs ^ ((d>>1)&3)) << 2) + vkl] = (u32)au[i] | ((u32)bu[i] << 16);
      }
    }

    // ---- QK^T for both strips, kf read once ----
    f32x16 stA = {}, stB = {};
    if (actB) {
#pragma unroll
      for (int kk = 0; kk < 4; kk++) {
        bf16x8 kf = *reinterpret_cast<const bf16x8*>(
            &Ks[q31*64 + ((((kk<<1) | hi) ^ (q31 & 7)) << 3)]);
        stA = __builtin_amdgcn_mfma_f32_32x32x16_bf16(kf, qfA[kk], stA, 0, 0, 0);
        stB = __builtin_amdgcn_mfma_f32_32x32x16_bf16(kf, qfB[kk], stB, 0, 0, 0);
      }
    } else {
#pragma unroll
      for (int kk = 0; kk < 4; kk++) {
        bf16x8 kf = *reinterpret_cast<const bf16x8*>(
            &Ks[q31*64 + ((((kk<<1) | hi) ^ (q31 & 7)) << 3)]);
        stA = __builtin_amdgcn_mfma_f32_32x32x16_bf16(kf, qfA[kk], stA, 0, 0, 0);
      }
    }
    asm volatile("s_waitcnt lgkmcnt(0)" ::: "memory");
    __builtin_amdgcn_sched_barrier(0);

    // ---- prefetch own next tile ----
    if (!lastown) {
      size_t off = (size_t)(kb + 96) * N1_;
#pragma unroll
      for (int r = 0; r < 4; r++)
        gload_lds16(ksrc + off + (size_t)(8*r) * N1_, (char*)Ks + r*1024);
#pragma unroll
      for (int r = 0; r < 2; r++) {
        vA[r] = *reinterpret_cast<const bf16x8*>(vsrc + off + r*8);
        vB[r] = *reinterpret_cast<const bf16x8*>(vsrc + off + r*8 + N1_);
      }
    }

    // ---- softmax + pack A ----
    if (kt == sA) {
#pragma unroll
      for (int r = 0; r < 16; r++) {
        int keyg = kb + (r&3) + 8*(r>>2) + 4*hi;
        if (keyg > qgA) stA[r] = -__builtin_inff();
      }
    }
    {
      float ts = 0.f;
#pragma unroll
      for (int r = 0; r < 16; r++) {
        float pp = exp2v(stA[r]);
        stA[r] = pp;
        ts += pp;
      }
      lA += ts;
    }
    bf16x8 pfA0, pfA1;
    {
      u32 pk[8];
#pragma unroll
      for (int m = 0; m < 8; m++) pk[m] = cvtpk(stA[2*m], stA[2*m+1]);
      asm volatile("v_permlane32_swap_b32 %0, %1" : "+v"(pk[0]), "+v"(pk[2]));
      asm volatile("v_permlane32_swap_b32 %0, %1" : "+v"(pk[1]), "+v"(pk[3]));
      asm volatile("v_permlane32_swap_b32 %0, %1" : "+v"(pk[4]), "+v"(pk[6]));
      asm volatile("v_permlane32_swap_b32 %0, %1" : "+v"(pk[5]), "+v"(pk[7]));
      u32x4 f0 = { pk[0], pk[1], pk[2], pk[3] };
      u32x4 f1 = { pk[4], pk[5], pk[6], pk[7] };
      pfA0 = __builtin_bit_cast(bf16x8, f0);
      pfA1 = __builtin_bit_cast(bf16x8, f1);
    }

    if (actB) {
      // ---- softmax + pack B ----
      if (kt == sB) {
#pragma unroll
        for (int r = 0; r < 16; r++) {
          int keyg = kb + (r&3) + 8*(r>>2) + 4*hi;
          if (keyg > qgB) stB[r] = -__builtin_inff();
        }
      }
      {
        float ts = 0.f;
#pragma unroll
        for (int r = 0; r < 16; r++) {
          float pp = exp2v(stB[r]);
          stB[r] = pp;
          ts += pp;
        }
        lB += ts;
      }
      bf16x8 pfB0, pfB1;
      {
        u32 pk[8];
#pragma unroll
        for (int m = 0; m < 8; m++) pk[m] = cvtpk(stB[2*m], stB[2*m+1]);
        asm volatile("v_permlane32_swap_b32 %0, %1" : "+v"(pk[0]), "+v"(pk[2]));
        asm volatile("v_permlane32_swap_b32 %0, %1" : "+v"(pk[1]), "+v"(pk[3]));
        asm volatile("v_permlane32_swap_b32 %0, %1" : "+v"(pk[4]), "+v"(pk[6]));
        asm volatile("v_permlane32_swap_b32 %0, %1" : "+v"(pk[5]), "+v"(pk[7]));
        u32x4 f0 = { pk[0], pk[1], pk[2], pk[3] };
        u32x4 f1 = { pk[4], pk[5], pk[6], pk[7] };
        pfB0 = __builtin_bit_cast(bf16x8, f0);
        pfB1 = __builtin_bit_cast(bf16x8, f1);
      }
      // ---- PV both strips, vf read once ----
#pragma unroll
      for (int dt = 0; dt < 2; dt++)
#pragma unroll
        for (int kc = 0; kc < 2; kc++) {
          int cs = (kc << 1) | hi;
          bf16x8 vf = *reinterpret_cast<const bf16x8*>(
              &Vt32[(32*dt + q31f)*16 + ((cs ^ swr) << 2)]);
          oaccA[dt] = __builtin_amdgcn_mfma_f32_32x32x16_bf16(vf, kc ? pfA1 : pfA0, oaccA[dt], 0, 0, 0);
          oaccB[dt] = __builtin_amdgcn_mfma_f32_32x32x16_bf16(vf, kc ? pfB1 : pfB0, oaccB[dt], 0, 0, 0);
        }
    } else {
      // ---- PV strip A only ----
#pragma unroll
      for (int dt = 0; dt < 2; dt++)
#pragma unroll
        for (int kc = 0; kc < 2; kc++) {
          int cs = (kc << 1) | hi;
          bf16x8 vf = *reinterpret_cast<const bf16x8*>(
              &Vt32[(32*dt + q31f)*16 + ((cs ^ swr) << 2)]);
          oaccA[dt] = __builtin_amdgcn_mfma_f32_32x32x16_bf16(vf, kc ? pfA1 : pfA0, oaccA[dt], 0, 0, 0);
        }
    }
  }
  lA += __shfl_xor(lA, 32);
  lB += __shfl_xor(lB, 32);

  // ---- merge strip A ----
  __syncthreads();
  if (w) {
    float* park = (float*)Sm[w];
#pragma unroll
    for (int dt = 0; dt < 2; dt++)
#pragma unroll
      for (int r = 0; r < 16; r++) park[(dt*16 + r)*64 + lane] = oaccA[dt][r];
    float* ml = (float*)Sm[0];
    ml[(w-1)*64 + lane] = lA;
  }
  __syncthreads();
  if (w == 0) {
    const float* ml = (const float*)Sm[0];
    float linv = 1.f / (lA + ml[lane] + ml[64 + lane]);
    const float* p1 = (const float*)Sm[1];
    const float* p2 = (const float*)Sm[2];
    u16* orow = attnout + (size_t)(b*T_ + qgA) * C_ + h*HD_;
#pragma unroll
    for (int dt = 0; dt < 2; dt++)
#pragma unroll
      for (int m = 0; m < 8; m++) {
        int e0 = (dt*16 + 2*m)*64 + lane, e1 = e0 + 64;
        float v0 = (oaccA[dt][2*m]   + p1[e0] + p2[e0]) * linv;
        float v1 = (oaccA[dt][2*m+1] + p1[e1] + p2[e1]) * linv;
        int d = 32*dt + 2*(m&1) + 8*(m>>1) + 4*hi;
        *reinterpret_cast<u32*>(orow + d) = cvtpk(v0, v1);
      }
  }
  __syncthreads();
  // ---- merge strip B ----
  if (w) {
    float* park = (float*)Sm[w];
#pragma unroll
    for (int dt = 0; dt < 2; dt++)
#pragma unroll
      for (int r = 0; r < 16; r++) park[(dt*16 + r)*64 + lane] = oaccB[dt][r];
    float* ml = (float*)Sm[0];
    ml[(w-1)*64 + lane] = lB;
  }
  __syncthreads();
  if (w == 0) {
    const float* ml = (const float*)Sm[0];
    float linv = 1.f / (lB + ml[lane] + ml[64 + lane]);
    const float* p1 = (const float*)Sm[1];
    const float* p2 = (const float*)Sm[2];
    u16* orow = attnout + (size_t)(b*T_ + qgB) * C_ + h*HD_;
#pragma unroll
    for (int dt = 0; dt < 2; dt++)
#pragma unroll
      for (int m = 0; m < 8; m++) {
        int e0 = (dt*16 + 2*m)*64 + lane, e1 = e0 + 64;
        float v0 = (oaccB[dt][2*m]   + p1[e0] + p2[e0]) * linv;
        float v1 = (oaccB[dt][2*m+1] + p1[e1] + p2[e1]) * linv;
        int d = 32*dt + 2*(m&1) + 8*(m>>1) + 4*hi;
        *reinterpret_cast<u32*>(orow + d) = cvtpk(v0, v1);
      }
  }
}

extern "C" void kernel_launch(void* const* d_in, const int* in_sizes, int n_in,
                              void* d_out, int out_size, void* d_ws, size_t ws_size,
                              hipStream_t stream) {
  const float* x     = (const float*)d_in[0];
  const float* w_qkv = (const float*)d_in[1];
  const float* w_out = (const float*)d_in[2];
  float* out = (float*)d_out;
  char* ws = (char*)d_ws;
  u16* xb    = (u16*)(ws);                         // 8 MB  : x bf16 (4096 x 1024)
  u16* wqkvT = (u16*)(ws + ((size_t)8  << 20));    // 6 MB  : w_qkv^T bf16 (3072 x 1024)
  u16* woutT = (u16*)(ws + ((size_t)14 << 20));    // 2 MB  : w_out^T bf16 (1024 x 1024)
  u16* qkvb  = (u16*)(ws + ((size_t)16 << 20));    // 24 MB : qkv bf16 (4096 x 3072)
  u16* attnb = (u16*)(ws + ((size_t)40 << 20));    // 8 MB  : attn out bf16 (4096 x 1024)

  prep_k<<<8192, 256, 0, stream>>>(x, w_qkv, w_out, xb, wqkvT, woutT);
  gemm256<<<dim3(16, 16), 512, 0, stream>>>(xb, wqkvT, qkvb);
  attn_kernel<<<1024, 192, 0, stream>>>(qkvb, attnb);
  gemm_bt<1><<<dim3(C_/128, BT_/128), 256, 0, stream>>>(attnb, woutT, (void*)out, BT_, C_, C_);
}

// Round 22
// 100.943 us; speedup vs baseline: 1.3540x; 1.0197x over previous
//
#include <hip/hip_runtime.h>
#include <hip/hip_bf16.h>
#include <stdint.h>
#include <math.h>

#define B_ 2
#define T_ 2048
#define C_ 1024
#define H_ 16
#define HD_ 64
#define BT_ (B_*T_)      // 4096 rows
#define N1_ (3*C_)       // 3072

typedef unsigned short u16;
typedef uint32_t u32;
typedef __attribute__((ext_vector_type(8))) short bf16x8;
typedef __attribute__((ext_vector_type(4))) float f32x4;
typedef __attribute__((ext_vector_type(16))) float f32x16;
typedef __attribute__((ext_vector_type(4))) unsigned int u32x4;

__device__ __forceinline__ u16 f2bf(float f) {
  __hip_bfloat16 h = __float2bfloat16(f);
  return *reinterpret_cast<u16*>(&h);
}
__device__ __forceinline__ float bf2f(u16 u) {
  u32 w = ((u32)u) << 16;
  return *reinterpret_cast<float*>(&w);
}
__device__ __forceinline__ u32 cvtpk(float lo, float hi) {
  u32 r;
  asm("v_cvt_pk_bf16_f32 %0, %1, %2" : "=v"(r) : "v"(lo), "v"(hi));
  return r;
}
__device__ __forceinline__ float exp2v(float x) {   // exact v_exp_f32 (2^x); -inf -> 0
  float r;
  asm("v_exp_f32 %0, %1" : "=v"(r) : "v"(x));
  return r;
}

__device__ __forceinline__ void gload_lds16(const void* g, void* l) {
  __builtin_amdgcn_global_load_lds(
      (const __attribute__((address_space(1))) uint32_t*)g,
      (__attribute__((address_space(3))) uint32_t*)l, 16, 0, 0);
}

// raw workgroup barrier WITHOUT __syncthreads' vmcnt(0) drain
#define BARX() do { asm volatile("" ::: "memory"); __builtin_amdgcn_s_barrier(); \
                    asm volatile("" ::: "memory"); } while (0)
// lgkm drain + scheduler fence (rule #18)
#define LGKM0() do { asm volatile("s_waitcnt lgkmcnt(0)" ::: "memory"); \
                     __builtin_amdgcn_sched_barrier(0); } while (0)

// ---------------- fused prep: cast x + transpose-cast both weights ----------------
__global__ __launch_bounds__(256) void prep_k(const float* __restrict__ x,
                                              const float* __restrict__ w_qkv,
                                              const float* __restrict__ w_out,
                                              u16* __restrict__ xb,
                                              u16* __restrict__ wqkvT,
                                              u16* __restrict__ woutT) {
  __shared__ float tile[32][33];
  int bid = blockIdx.x;
  if (bid < 4096) {
    int idx = bid * 1024 + threadIdx.x * 4;
    float4 v = *reinterpret_cast<const float4*>(x + idx);
    u16 tmp[4] = {f2bf(v.x), f2bf(v.y), f2bf(v.z), f2bf(v.w)};
    *reinterpret_cast<uint2*>(xb + idx) = *reinterpret_cast<const uint2*>(tmp);
    return;
  }
  const float* w;
  u16* wt;
  int N, tb;
  if (bid < 7168) { tb = bid - 4096; w = w_qkv; wt = wqkvT; N = N1_; }
  else            { tb = bid - 7168; w = w_out; wt = woutT; N = C_;  }
  int nx = N >> 5;
  int n0 = (tb % nx) * 32, k0 = (tb / nx) * 32;
  int tx = threadIdx.x & 31, ty = threadIdx.x >> 5;
#pragma unroll
  for (int i = 0; i < 4; i++)
    tile[ty + i*8][tx] = w[(size_t)(k0 + ty + i*8) * N + n0 + tx];
  __syncthreads();
#pragma unroll
  for (int i = 0; i < 4; i++)
    wt[(size_t)(n0 + ty + i*8) * 1024 + k0 + tx] = f2bf(tile[tx][ty + i*8]);
}

// ---------------- QKV GEMM: 256x192, BK=64, 2-phase choreography (R19-proven) ----------------
__global__ __launch_bounds__(512, 2) void gemm256(const u16* __restrict__ A, const u16* __restrict__ Bt,
                                                  u16* __restrict__ Cc) {
  __shared__ u16 As[2][256*64];
  __shared__ u16 Bs[2][192*64];
  int tid = threadIdx.x, w = tid >> 6, lane = tid & 63;
  int m0 = blockIdx.y * 256, n0 = blockIdx.x * 192;
  int wm = (w >> 2) * 128, wn = (w & 3) * 48;
  f32x4 acc[8][3] = {};

  size_t aoff[4];
  size_t boff[3];
#pragma unroll
  for (int i = 0; i < 4; i++) {
    int c = i*512 + tid, row = c >> 3;
    aoff[i] = (size_t)(m0 + row) * 1024 + (size_t)((((c & 7) ^ (row & 7))) * 8);
  }
#pragma unroll
  for (int i = 0; i < 3; i++) {
    int c = i*512 + tid, row = c >> 3;
    boff[i] = (size_t)(n0 + row) * 1024 + (size_t)((((c & 7) ^ (row & 7))) * 8);
  }
  int dstc = w * 1024;

  int r15 = lane & 15, kq = lane >> 4;
  int slot0 = (kq ^ (r15 & 7)) * 8;
  int abase = (wm + r15) * 64;
  int bbase = (wn + r15) * 64;

#pragma unroll
  for (int i = 0; i < 4; i++)
    gload_lds16(A + aoff[i], (char*)&As[0][0] + i*8192 + dstc);
#pragma unroll
  for (int i = 0; i < 3; i++)
    gload_lds16(Bt + boff[i], (char*)&Bs[0][0] + i*8192 + dstc);

  for (int t = 0; t < 16; ++t) {
    int buf = t & 1;
    const u16* Ab = &As[buf][0];
    const u16* Bb = &Bs[buf][0];
    int slot1 = slot0 ^ 32;
    bf16x8 af[8], bfv[3];

    asm volatile("s_waitcnt vmcnt(0)" ::: "memory");
    BARX();

#pragma unroll
    for (int nf = 0; nf < 3; nf++) bfv[nf] = *reinterpret_cast<const bf16x8*>(&Bb[bbase + nf*1024 + slot0]);
#pragma unroll
    for (int mf = 0; mf < 8; mf++) af[mf] = *reinterpret_cast<const bf16x8*>(&Ab[abase + mf*1024 + slot0]);
    if (t < 15) {
      int ko = (t + 1) * 64;
#pragma unroll
      for (int i = 0; i < 4; i++)
        gload_lds16(A + aoff[i] + ko, (char*)&As[buf ^ 1][0] + i*8192 + dstc);
#pragma unroll
      for (int i = 0; i < 3; i++)
        gload_lds16(Bt + boff[i] + ko, (char*)&Bs[buf ^ 1][0] + i*8192 + dstc);
    }
    BARX();
    LGKM0();
    __builtin_amdgcn_s_setprio(1);
#pragma unroll
    for (int mf = 0; mf < 8; mf++)
#pragma unroll
      for (int nf = 0; nf < 3; nf++)
        acc[mf][nf] = __builtin_amdgcn_mfma_f32_16x16x32_bf16(af[mf], bfv[nf], acc[mf][nf], 0, 0, 0);
    __builtin_amdgcn_s_setprio(0);

#pragma unroll
    for (int nf = 0; nf < 3; nf++) bfv[nf] = *reinterpret_cast<const bf16x8*>(&Bb[bbase + nf*1024 + slot1]);
#pragma unroll
    for (int mf = 0; mf < 8; mf++) af[mf] = *reinterpret_cast<const bf16x8*>(&Ab[abase + mf*1024 + slot1]);
    BARX();
    LGKM0();
    __builtin_amdgcn_s_setprio(1);
#pragma unroll
    for (int mf = 0; mf < 8; mf++)
#pragma unroll
      for (int nf = 0; nf < 3; nf++)
        acc[mf][nf] = __builtin_amdgcn_mfma_f32_16x16x32_bf16(af[mf], bfv[nf], acc[mf][nf], 0, 0, 0);
    __builtin_amdgcn_s_setprio(0);
  }

  int rg = kq * 4;
#pragma unroll
  for (int mf = 0; mf < 8; mf++)
#pragma unroll
    for (int nf = 0; nf < 3; nf++) {
      size_t basei = (size_t)(m0 + wm + mf*16 + rg) * N1_ + (size_t)(n0 + wn + nf*16 + r15);
#pragma unroll
      for (int r = 0; r < 4; r++)
        Cc[basei + (size_t)r * N1_] = f2bf(acc[mf][nf][r]);
    }
}

// ---------------- out-proj GEMM: 128x128, BK=64, 8 waves, gemm256 choreography ----------------
// A (4096x1024 bf16), Bt (1024x1024 bf16 N-major) -> out (4096x1024 f32).
// Grid (8,32)=256 blocks=1/CU, 8 waves (2Mx4N), per-wave 64x32 (4x2 frags).
// Same proven cert/phase pattern as gemm256; 64KB LDS.
__global__ __launch_bounds__(512, 1) void gemm128(const u16* __restrict__ A, const u16* __restrict__ Bt,
                                                  float* __restrict__ Co) {
  __shared__ u16 As[2][128*64];
  __shared__ u16 Bs[2][128*64];
  int tid = threadIdx.x, w = tid >> 6, lane = tid & 63;
  int m0 = blockIdx.y * 128, n0 = blockIdx.x * 128;
  int wm = (w >> 2) * 64, wn = (w & 3) * 32;
  f32x4 acc[4][2] = {};

  size_t aoff[2], boff[2];
#pragma unroll
  for (int i = 0; i < 2; i++) {
    int c = i*512 + tid, row = c >> 3;
    aoff[i] = (size_t)(m0 + row) * 1024 + (size_t)((((c & 7) ^ (row & 7))) * 8);
    boff[i] = (size_t)(n0 + row) * 1024 + (size_t)((((c & 7) ^ (row & 7))) * 8);
  }
  int dstc = w * 1024;

  int r15 = lane & 15, kq = lane >> 4;
  int slot0 = (kq ^ (r15 & 7)) * 8;
  int abase = (wm + r15) * 64;
  int bbase = (wn + r15) * 64;

#pragma unroll
  for (int i = 0; i < 2; i++) {
    gload_lds16(A  + aoff[i], (char*)&As[0][0] + i*8192 + dstc);
    gload_lds16(Bt + boff[i], (char*)&Bs[0][0] + i*8192 + dstc);
  }

  for (int t = 0; t < 16; ++t) {
    int buf = t & 1;
    const u16* Ab = &As[buf][0];
    const u16* Bb = &Bs[buf][0];
    int slot1 = slot0 ^ 32;
    bf16x8 af[4], bfv[2];

    asm volatile("s_waitcnt vmcnt(0)" ::: "memory");
    BARX();

    // phase 0: reads(ks0) | stage t+1; bar; 8 MFMA
#pragma unroll
    for (int nf = 0; nf < 2; nf++) bfv[nf] = *reinterpret_cast<const bf16x8*>(&Bb[bbase + nf*1024 + slot0]);
#pragma unroll
    for (int mf = 0; mf < 4; mf++) af[mf] = *reinterpret_cast<const bf16x8*>(&Ab[abase + mf*1024 + slot0]);
    if (t < 15) {
      int ko = (t + 1) * 64;
#pragma unroll
      for (int i = 0; i < 2; i++) {
        gload_lds16(A  + aoff[i] + ko, (char*)&As[buf ^ 1][0] + i*8192 + dstc);
        gload_lds16(Bt + boff[i] + ko, (char*)&Bs[buf ^ 1][0] + i*8192 + dstc);
      }
    }
    BARX();
    LGKM0();
    __builtin_amdgcn_s_setprio(1);
#pragma unroll
    for (int mf = 0; mf < 4; mf++)
#pragma unroll
      for (int nf = 0; nf < 2; nf++)
        acc[mf][nf] = __builtin_amdgcn_mfma_f32_16x16x32_bf16(af[mf], bfv[nf], acc[mf][nf], 0, 0, 0);
    __builtin_amdgcn_s_setprio(0);

    // phase 1: reads(ks1); bar; 8 MFMA
#pragma unroll
    for (int nf = 0; nf < 2; nf++) bfv[nf] = *reinterpret_cast<const bf16x8*>(&Bb[bbase + nf*1024 + slot1]);
#pragma unroll
    for (int mf = 0; mf < 4; mf++) af[mf] = *reinterpret_cast<const bf16x8*>(&Ab[abase + mf*1024 + slot1]);
    BARX();
    LGKM0();
    __builtin_amdgcn_s_setprio(1);
#pragma unroll
    for (int mf = 0; mf < 4; mf++)
#pragma unroll
      for (int nf = 0; nf < 2; nf++)
        acc[mf][nf] = __builtin_amdgcn_mfma_f32_16x16x32_bf16(af[mf], bfv[nf], acc[mf][nf], 0, 0, 0);
    __builtin_amdgcn_s_setprio(0);
  }

  int rg = kq * 4;
#pragma unroll
  for (int mf = 0; mf < 4; mf++)
#pragma unroll
    for (int nf = 0; nf < 2; nf++) {
      size_t basei = (size_t)(m0 + wm + mf*16 + rg) * C_ + (size_t)(n0 + wn + nf*16 + r15);
#pragma unroll
      for (int r = 0; r < 4; r++)
        Co[basei + (size_t)r * C_] = acc[mf][nf][r];
    }
}

// ---------------- causal flash attention: dual-strip shared-K/V, no-spill (R21-proven) ----------------
__global__ __launch_bounds__(192, 2) void attn_kernel(const u16* __restrict__ qkv, u16* __restrict__ attnout) {
  __shared__ u16 Sm[3][4096];    // per wave: K tile [0..2047], V^T tile [2048..4095]
  int tid = threadIdx.x;
  int w = tid >> 6, lane = tid & 63;
  int q31 = lane & 31, hi = lane >> 5;
  int lid = blockIdx.x;
  int xcd = lid & 7, j = lid >> 3;
  int bh = xcd * 4 + (j & 3);
  int p = j >> 2;                // 0..31
  int b = bh >> 4, h = bh & 15;
  const u16* base = qkv + (size_t)b * T_ * N1_;

  u16* Ks = Sm[w];
  u32* Vt32 = reinterpret_cast<u32*>(Sm[w] + 2048);

  const u16* ksrc = base + C_ + h*HD_ + (size_t)(lane >> 3) * N1_
                    + (size_t)(((lane & 7) ^ ((lane >> 3) & 7)) * 8);
  int kp2 = lane & 15, dc = (lane >> 4) * 16;
  int vcs = kp2 >> 2, vkl = kp2 & 3;
  int vflip = (lane >> 4) & 1;
  const u16* vsrc = base + 2*C_ + h*HD_ + (size_t)(2*kp2) * N1_ + dc;
  const float QSC = 0.125f * 1.44269504088896f;
  int swr = (q31 >> 1) & 3;
  int q31f = q31 ^ ((q31 >> 4) & 1);

  int sA = 63 - p, sB = p;
  int qgA = sA * 32 + q31, qgB = sB * 32 + q31;
  int nktU = sA + 1;

  bf16x8 qfA[4], qfB[4];
  {
    const u16* qrowA = base + (size_t)qgA * N1_ + h * HD_;
    const u16* qrowB = base + (size_t)qgB * N1_ + h * HD_;
#pragma unroll
    for (int kk = 0; kk < 4; kk++) {
      bf16x8 ra = *reinterpret_cast<const bf16x8*>(qrowA + kk*16 + hi*8);
      bf16x8 rb = *reinterpret_cast<const bf16x8*>(qrowB + kk*16 + hi*8);
      const u16* pa = (const u16*)&ra;
      const u16* pb = (const u16*)&rb;
      u32x4 qa, qb;
#pragma unroll
      for (int jj = 0; jj < 4; jj++) {
        qa[jj] = cvtpk(bf2f(pa[2*jj]) * QSC, bf2f(pa[2*jj+1]) * QSC);
        qb[jj] = cvtpk(bf2f(pb[2*jj]) * QSC, bf2f(pb[2*jj+1]) * QSC);
      }
      qfA[kk] = __builtin_bit_cast(bf16x8, qa);
      qfB[kk] = __builtin_bit_cast(bf16x8, qb);
    }
  }

  f32x16 oaccA[2] = {}, oaccB[2] = {};
  float lA = 0.f, lB = 0.f;

  bf16x8 vA[2], vB[2];
  {
    size_t off0 = (size_t)(w * 32) * N1_;
#pragma unroll
    for (int r = 0; r < 4; r++)
      gload_lds16(ksrc + off0 + (size_t)(8*r) * N1_, (char*)Ks + r*1024);
#pragma unroll
    for (int r = 0; r < 2; r++) {
      vA[r] = *reinterpret_cast<const bf16x8*>(vsrc + off0 + r*8);
      vB[r] = *reinterpret_cast<const bf16x8*>(vsrc + off0 + r*8 + N1_);
    }
  }

  for (int kt = w; kt < nktU; kt += 3) {
    int kb = kt * 32;
    bool lastown = (kt + 3 >= nktU);
    bool actB = (kt <= sB);

    asm volatile("s_waitcnt vmcnt(0)" ::: "memory");

#pragma unroll
    for (int r2 = 0; r2 < 2; r2++) {
      const u16* au = (const u16*)&vA[r2];
      const u16* bu = (const u16*)&vB[r2];
#pragma unroll
      for (int i = 0; i < 8; i++) {
        int d = dc + r2*8 + i;
        Vt32[(d ^ vflip)*16 + ((vcs ^ ((d>>1)&3)) << 2) + vkl] = (u32)au[i] | ((u32)bu[i] << 16);
      }
    }

    f32x16 stA = {}, stB = {};
    if (actB) {
#pragma unroll
      for (int kk = 0; kk < 4; kk++) {
        bf16x8 kf = *reinterpret_cast<const bf16x8*>(
            &Ks[q31*64 + ((((kk<<1) | hi) ^ (q31 & 7)) << 3)]);
        stA = __builtin_amdgcn_mfma_f32_32x32x16_bf16(kf, qfA[kk], stA, 0, 0, 0);
        stB = __builtin_amdgcn_mfma_f32_32x32x16_bf16(kf, qfB[kk], stB, 0, 0, 0);
      }
    } else {
#pragma unroll
      for (int kk = 0; kk < 4; kk++) {
        bf16x8 kf = *reinterpret_cast<const bf16x8*>(
            &Ks[q31*64 + ((((kk<<1) | hi) ^ (q31 & 7)) << 3)]);
        stA = __builtin_amdgcn_mfma_f32_32x32x16_bf16(kf, qfA[kk], stA, 0, 0, 0);
      }
    }
    asm volatile("s_waitcnt lgkmcnt(0)" ::: "memory");
    __builtin_amdgcn_sched_barrier(0);

    if (!lastown) {
      size_t off = (size_t)(kb + 96) * N1_;
#pragma unroll
      for (int r = 0; r < 4; r++)
        gload_lds16(ksrc + off + (size_t)(8*r) * N1_, (char*)Ks + r*1024);
#pragma unroll
      for (int r = 0; r < 2; r++) {
        vA[r] = *reinterpret_cast<const bf16x8*>(vsrc + off + r*8);
        vB[r] = *reinterpret_cast<const bf16x8*>(vsrc + off + r*8 + N1_);
      }
    }

    if (kt == sA) {
#pragma unroll
      for (int r = 0; r < 16; r++) {
        int keyg = kb + (r&3) + 8*(r>>2) + 4*hi;
        if (keyg > qgA) stA[r] = -__builtin_inff();
      }
    }
    {
      float ts = 0.f;
#pragma unroll
      for (int r = 0; r < 16; r++) {
        float pp = exp2v(stA[r]);
        stA[r] = pp;
        ts += pp;
      }
      lA += ts;
    }
    bf16x8 pfA0, pfA1;
    {
      u32 pk[8];
#pragma unroll
      for (int m = 0; m < 8; m++) pk[m] = cvtpk(stA[2*m], stA[2*m+1]);
      asm volatile("v_permlane32_swap_b32 %0, %1" : "+v"(pk[0]), "+v"(pk[2]));
      asm volatile("v_permlane32_swap_b32 %0, %1" : "+v"(pk[1]), "+v"(pk[3]));
      asm volatile("v_permlane32_swap_b32 %0, %1" : "+v"(pk[4]), "+v"(pk[6]));
      asm volatile("v_permlane32_swap_b32 %0, %1" : "+v"(pk[5]), "+v"(pk[7]));
      u32x4 f0 = { pk[0], pk[1], pk[2], pk[3] };
      u32x4 f1 = { pk[4], pk[5], pk[6], pk[7] };
      pfA0 = __builtin_bit_cast(bf16x8, f0);
      pfA1 = __builtin_bit_cast(bf16x8, f1);
    }

    if (actB) {
      if (kt == sB) {
#pragma unroll
        for (int r = 0; r < 16; r++) {
          int keyg = kb + (r&3) + 8*(r>>2) + 4*hi;
          if (keyg > qgB) stB[r] = -__builtin_inff();
        }
      }
      {
        float ts = 0.f;
#pragma unroll
        for (int r = 0; r < 16; r++) {
          float pp = exp2v(stB[r]);
          stB[r] = pp;
          ts += pp;
        }
        lB += ts;
      }
      bf16x8 pfB0, pfB1;
      {
        u32 pk[8];
#pragma unroll
        for (int m = 0; m < 8; m++) pk[m] = cvtpk(stB[2*m], stB[2*m+1]);
        asm volatile("v_permlane32_swap_b32 %0, %1" : "+v"(pk[0]), "+v"(pk[2]));
        asm volatile("v_permlane32_swap_b32 %0, %1" : "+v"(pk[1]), "+v"(pk[3]));
        asm volatile("v_permlane32_swap_b32 %0, %1" : "+v"(pk[4]), "+v"(pk[6]));
        asm volatile("v_permlane32_swap_b32 %0, %1" : "+v"(pk[5]), "+v"(pk[7]));
        u32x4 f0 = { pk[0], pk[1], pk[2], pk[3] };
        u32x4 f1 = { pk[4], pk[5], pk[6], pk[7] };
        pfB0 = __builtin_bit_cast(bf16x8, f0);
        pfB1 = __builtin_bit_cast(bf16x8, f1);
      }
#pragma unroll
      for (int dt = 0; dt < 2; dt++)
#pragma unroll
        for (int kc = 0; kc < 2; kc++) {
          int cs = (kc << 1) | hi;
          bf16x8 vf = *reinterpret_cast<const bf16x8*>(
              &Vt32[(32*dt + q31f)*16 + ((cs ^ swr) << 2)]);
          oaccA[dt] = __builtin_amdgcn_mfma_f32_32x32x16_bf16(vf, kc ? pfA1 : pfA0, oaccA[dt], 0, 0, 0);
          oaccB[dt] = __builtin_amdgcn_mfma_f32_32x32x16_bf16(vf, kc ? pfB1 : pfB0, oaccB[dt], 0, 0, 0);
        }
    } else {
#pragma unroll
      for (int dt = 0; dt < 2; dt++)
#pragma unroll
        for (int kc = 0; kc < 2; kc++) {
          int cs = (kc << 1) | hi;
          bf16x8 vf = *reinterpret_cast<const bf16x8*>(
              &Vt32[(32*dt + q31f)*16 + ((cs ^ swr) << 2)]);
          oaccA[dt] = __builtin_amdgcn_mfma_f32_32x32x16_bf16(vf, kc ? pfA1 : pfA0, oaccA[dt], 0, 0, 0);
        }
    }
  }
  lA += __shfl_xor(lA, 32);
  lB += __shfl_xor(lB, 32);

  // ---- merge strip A ----
  __syncthreads();
  if (w) {
    float* park = (float*)Sm[w];
#pragma unroll
    for (int dt = 0; dt < 2; dt++)
#pragma unroll
      for (int r = 0; r < 16; r++) park[(dt*16 + r)*64 + lane] = oaccA[dt][r];
    float* ml = (float*)Sm[0];
    ml[(w-1)*64 + lane] = lA;
  }
  __syncthreads();
  if (w == 0) {
    const float* ml = (const float*)Sm[0];
    float linv = 1.f / (lA + ml[lane] + ml[64 + lane]);
    const float* p1 = (const float*)Sm[1];
    const float* p2 = (const float*)Sm[2];
    u16* orow = attnout + (size_t)(b*T_ + qgA) * C_ + h*HD_;
#pragma unroll
    for (int dt = 0; dt < 2; dt++)
#pragma unroll
      for (int m = 0; m < 8; m++) {
        int e0 = (dt*16 + 2*m)*64 + lane, e1 = e0 + 64;
        float v0 = (oaccA[dt][2*m]   + p1[e0] + p2[e0]) * linv;
        float v1 = (oaccA[dt][2*m+1] + p1[e1] + p2[e1]) * linv;
        int d = 32*dt + 2*(m&1) + 8*(m>>1) + 4*hi;
        *reinterpret_cast<u32*>(orow + d) = cvtpk(v0, v1);
      }
  }
  __syncthreads();
  // ---- merge strip B ----
  if (w) {
    float* park = (float*)Sm[w];
#pragma unroll
    for (int dt = 0; dt < 2; dt++)
#pragma unroll
      for (int r = 0; r < 16; r++) park[(dt*16 + r)*64 + lane] = oaccB[dt][r];
    float* ml = (float*)Sm[0];
    ml[(w-1)*64 + lane] = lB;
  }
  __syncthreads();
  if (w == 0) {
    const float* ml = (const float*)Sm[0];
    float linv = 1.f / (lB + ml[lane] + ml[64 + lane]);
    const float* p1 = (const float*)Sm[1];
    const float* p2 = (const float*)Sm[2];
    u16* orow = attnout + (size_t)(b*T_ + qgB) * C_ + h*HD_;
#pragma unroll
    for (int dt = 0; dt < 2; dt++)
#pragma unroll
      for (int m = 0; m < 8; m++) {
        int e0 = (dt*16 + 2*m)*64 + lane, e1 = e0 + 64;
        float v0 = (oaccB[dt][2*m]   + p1[e0] + p2[e0]) * linv;
        float v1 = (oaccB[dt][2*m+1] + p1[e1] + p2[e1]) * linv;
        int d = 32*dt + 2*(m&1) + 8*(m>>1) + 4*hi;
        *reinterpret_cast<u32*>(orow + d) = cvtpk(v0, v1);
      }
  }
}

extern "C" void kernel_launch(void* const* d_in, const int* in_sizes, int n_in,
                              void* d_out, int out_size, void* d_ws, size_t ws_size,
                              hipStream_t stream) {
  const float* x     = (const float*)d_in[0];
  const float* w_qkv = (const float*)d_in[1];
  const float* w_out = (const float*)d_in[2];
  float* out = (float*)d_out;
  char* ws = (char*)d_ws;
  u16* xb    = (u16*)(ws);                         // 8 MB  : x bf16 (4096 x 1024)
  u16* wqkvT = (u16*)(ws + ((size_t)8  << 20));    // 6 MB  : w_qkv^T bf16 (3072 x 1024)
  u16* woutT = (u16*)(ws + ((size_t)14 << 20));    // 2 MB  : w_out^T bf16 (1024 x 1024)
  u16* qkvb  = (u16*)(ws + ((size_t)16 << 20));    // 24 MB : qkv bf16 (4096 x 3072)
  u16* attnb = (u16*)(ws + ((size_t)40 << 20));    // 8 MB  : attn out bf16 (4096 x 1024)

  prep_k<<<8192, 256, 0, stream>>>(x, w_qkv, w_out, xb, wqkvT, woutT);
  gemm256<<<dim3(16, 16), 512, 0, stream>>>(xb, wqkvT, qkvb);
  attn_kernel<<<1024, 192, 0, stream>>>(qkvb, attnb);
  gemm128<<<dim3(8, 32), 512, 0, stream>>>(attnb, woutT, out);
}